// Round 1
// baseline (449.575 us; speedup 1.0000x reference)
//
#include <hip/hip_runtime.h>
#include <hip/hip_bf16.h>
#include <math.h>

// ---------------------------------------------------------------------------
// A3T-GCN two-layer, restructured:
//   - H == 0 in every tgcn_cell  =>  R gate dead, cell = (1-Z)*tanh(...)
//   - gcn(x,W,b) = (A_hat x) W + b  =>  propagate features once, fold W@Wl_top
//   - layer2: channels 0..31 period-independent, channel 32 = time;
//     A_hat(time)[:,p] == (A_hat x1)[:, ch 12+p]  => reuse layer-1 propagation
// Pipeline:
//   zero -> count(deg) -> scan(rowptr)+dinv -> scatter(CSR) -> prep(fold weights)
//   -> agg1+layer1 gates -> agg2(h) -> layer2 gates + final MLP
// ---------------------------------------------------------------------------

__global__ void zero_ints(int* __restrict__ a, int n) {
    int i = blockIdx.x * blockDim.x + threadIdx.x;
    if (i < n) a[i] = 0;
}

__global__ void count_edges(const int* __restrict__ dst, int* __restrict__ cnt, int E) {
    int e = blockIdx.x * blockDim.x + threadIdx.x;
    if (e < E) atomicAdd(&cnt[dst[e]], 1);
}

__global__ __launch_bounds__(1024) void scan_dinv(const int* __restrict__ cnt,
                                                  int* __restrict__ rowptr,
                                                  float* __restrict__ dinv, int n) {
    __shared__ int sh[1024];
    __shared__ int carry;
    int tid = threadIdx.x;
    if (tid == 0) carry = 0;
    __syncthreads();
    for (int base = 0; base < n; base += 1024) {
        int i = base + tid;
        int v = (i < n) ? cnt[i] : 0;
        if (i < n) dinv[i] = rsqrtf((float)v + 1.0f);
        sh[tid] = v;
        __syncthreads();
        for (int off = 1; off < 1024; off <<= 1) {
            int t = (tid >= off) ? sh[tid - off] : 0;
            __syncthreads();
            sh[tid] += t;
            __syncthreads();
        }
        if (i < n) rowptr[i] = carry + sh[tid] - v;  // exclusive
        __syncthreads();
        if (tid == 0) carry += sh[1023];
        __syncthreads();
    }
    if (tid == 0) rowptr[n] = carry;
}

__global__ void scatter_edges(const int* __restrict__ src, const int* __restrict__ dst,
                              const float* __restrict__ dinv, const int* __restrict__ rowptr,
                              int* __restrict__ cursor, int* __restrict__ col,
                              float* __restrict__ wgt, int E) {
    int e = blockIdx.x * blockDim.x + threadIdx.x;
    if (e >= E) return;
    int s = src[e], d = dst[e];
    int pos = atomicAdd(&cursor[d], 1);
    int idx = rowptr[d] + pos;
    col[idx] = s;
    wgt[idx] = dinv[s] * dinv[d];
}

// small[] layout (floats):
//   [0:32)a0z [32:64)a1z [64:96)c1z [96:128)a0h [128:160)a1h [160:192)c1h [192:204)probs1
//   [256:2304) M2z   [2304:4352) M2h
//   [4352:4416) q2z [4416:4480) q2h [4480:4544) c2z [4544:4608) c2h [4608:4620) probs2
__global__ __launch_bounds__(256) void prep_kernel(
    const float* __restrict__ W1, const float* __restrict__ b1,
    const float* __restrict__ Wl1, const float* __restrict__ bl1,
    const float* __restrict__ att1,
    const float* __restrict__ W2, const float* __restrict__ b2,
    const float* __restrict__ Wl2, const float* __restrict__ bl2,
    const float* __restrict__ att2, float* __restrict__ small) {
    int tid = threadIdx.x;
    // layer-1 folded: W1[g] (2x32) @ Wl1[g][:32,:] (32x32), plus bias fold
    for (int t = tid; t < 192; t += blockDim.x) {
        int which = t >> 5, hh = t & 31;
        int g = (which < 3) ? 0 : 2;
        int kind = which % 3;  // 0:a0 1:a1 2:c
        const float* Wl = Wl1 + g * 64 * 32;
        float s = 0.f;
        if (kind < 2) {
            const float* Wr = W1 + g * 2 * 32 + kind * 32;
            for (int k = 0; k < 32; ++k) s += Wr[k] * Wl[k * 32 + hh];
        } else {
            const float* br = b1 + g * 32;
            for (int k = 0; k < 32; ++k) s += br[k] * Wl[k * 32 + hh];
            s += bl1[g * 32 + hh];
        }
        small[t] = s;
    }
    // layer-2 folded M: W2[g][:32,:] (32x64) @ Wl2[g][:64,:] (64x64)
    for (int t = tid; t < 4096; t += blockDim.x) {
        int gg = t >> 11;
        int rem = t & 2047;
        int i = rem >> 6, j = rem & 63;
        int g = gg ? 2 : 0;
        const float* Wl = Wl2 + g * 128 * 64;
        const float* Wr = W2 + g * 33 * 64 + i * 64;
        float s = 0.f;
        for (int k = 0; k < 64; ++k) s += Wr[k] * Wl[k * 64 + j];
        small[256 + gg * 2048 + i * 64 + j] = s;
    }
    // q (time row) and c (bias fold)
    for (int t = tid; t < 256; t += blockDim.x) {
        int which = t >> 6, j = t & 63;
        int g = (which == 0 || which == 2) ? 0 : 2;
        const float* Wl = Wl2 + g * 128 * 64;
        float s = 0.f;
        if (which < 2) {
            const float* Wr = W2 + g * 33 * 64 + 32 * 64;
            for (int k = 0; k < 64; ++k) s += Wr[k] * Wl[k * 64 + j];
        } else {
            const float* br = b2 + g * 64;
            for (int k = 0; k < 64; ++k) s += br[k] * Wl[k * 64 + j];
            s += bl2[g * 64 + j];
        }
        small[4352 + which * 64 + j] = s;
    }
    if (tid == 0) {  // softmaxes (12 elements each)
        float mx = att1[0];
        for (int p = 1; p < 12; ++p) mx = fmaxf(mx, att1[p]);
        float e[12], sm = 0.f;
        for (int p = 0; p < 12; ++p) { e[p] = expf(att1[p] - mx); sm += e[p]; }
        for (int p = 0; p < 12; ++p) small[192 + p] = e[p] / sm;
        mx = att2[0];
        for (int p = 1; p < 12; ++p) mx = fmaxf(mx, att2[p]);
        sm = 0.f;
        for (int p = 0; p < 12; ++p) { e[p] = expf(att2[p] - mx); sm += e[p]; }
        for (int p = 0; p < 12; ++p) small[4608 + p] = e[p] / sm;
    }
}

// One 32-lane group per node. Lanes 0..23 aggregate A_hat x1 (24 ch);
// then lanes act as h-channels (0..31) for the collapsed layer-1 gates.
__global__ __launch_bounds__(256) void agg1_layer1(
    const float* __restrict__ X, const int* __restrict__ rowptr,
    const int* __restrict__ col, const float* __restrict__ wgt,
    const float* __restrict__ dinv, const float* __restrict__ small,
    float* __restrict__ hout, float* __restrict__ atime, int n) {
    int lane = threadIdx.x & 31;
    int node = (blockIdx.x * blockDim.x + threadIdx.x) >> 5;
    if (node >= n) return;
    float acc = 0.f;
    {
        float dn = dinv[node];
        int beg = rowptr[node], end = rowptr[node + 1];
        if (lane < 24) {
            acc = dn * dn * X[node * 24 + lane];
            for (int j = beg; j < end; ++j)
                acc = fmaf(wgt[j], X[col[j] * 24 + lane], acc);
        }
    }
    if (lane >= 12 && lane < 24) atime[node * 12 + lane - 12] = acc;
    float a0z = small[lane], a1z = small[32 + lane], c1z = small[64 + lane];
    float a0h = small[96 + lane], a1h = small[128 + lane], c1h = small[160 + lane];
    float hs = 0.f;
    for (int p = 0; p < 12; ++p) {
        float x0 = __shfl(acc, p, 32);
        float x1 = __shfl(acc, 12 + p, 32);
        float z = 1.f / (1.f + __expf(-fmaf(x0, a0z, fmaf(x1, a1z, c1z))));
        float ht = tanhf(fmaf(x0, a0h, fmaf(x1, a1h, c1h)));
        hs = fmaf(small[192 + p] * (1.f - z), ht, hs);
    }
    hout[node * 32 + lane] = fmaxf(hs, 0.f);
}

// A_hat applied to h (32 channels) -> ahh
__global__ __launch_bounds__(256) void agg2(
    const float* __restrict__ h, const int* __restrict__ rowptr,
    const int* __restrict__ col, const float* __restrict__ wgt,
    const float* __restrict__ dinv, float* __restrict__ ahh, int n) {
    int lane = threadIdx.x & 31;
    int node = (blockIdx.x * blockDim.x + threadIdx.x) >> 5;
    if (node >= n) return;
    float dn = dinv[node];
    float acc = dn * dn * h[node * 32 + lane];
    int beg = rowptr[node], end = rowptr[node + 1];
    for (int j = beg; j < end; ++j)
        acc = fmaf(wgt[j], h[col[j] * 32 + lane], acc);
    ahh[node * 32 + lane] = acc;
}

// One 64-lane wave per node: lane = layer-2 channel j.
// LDS: [0:2048)M2z [2048:4096)M2h [4096..)q2z q2h c2z c2h [4352:4364)probs2
//      [4364:6412)lw1 [6412:6444)lb1 [6444:6828)lw2 [6828:6840)lb2
__global__ __launch_bounds__(256) void layer2_final(
    const float* __restrict__ ahh, const float* __restrict__ atime,
    const float* __restrict__ small, const float* __restrict__ lw1,
    const float* __restrict__ lb1, const float* __restrict__ lw2,
    const float* __restrict__ lb2, float* __restrict__ out, int n) {
    __shared__ float sm[6848];
    for (int i = threadIdx.x; i < 4364; i += blockDim.x) sm[i] = small[256 + i];
    for (int i = threadIdx.x; i < 2048; i += blockDim.x) sm[4364 + i] = lw1[i];
    for (int i = threadIdx.x; i < 32; i += blockDim.x) sm[6412 + i] = lb1[i];
    for (int i = threadIdx.x; i < 384; i += blockDim.x) sm[6444 + i] = lw2[i];
    for (int i = threadIdx.x; i < 12; i += blockDim.x) sm[6828 + i] = lb2[i];
    __syncthreads();
    int lane = threadIdx.x & 63;
    int wid = threadIdx.x >> 6;
    for (int node = blockIdx.x * 4 + wid; node < n; node += gridDim.x * 4) {
        float ahv = ahh[node * 32 + (lane & 31)];
        float p0z = sm[4480 + lane], p0h = sm[4544 - 4352 + 4288 + 0];  // placeholder fixed below
        p0z = sm[4480 - 4352 + 4096 + lane];   // c2z at sm[4480-4352+4096]=sm[4224]
        p0h = sm[4544 - 4352 + 4096 + lane];   // c2h at sm[4288]
        #pragma unroll
        for (int i = 0; i < 32; ++i) {
            float ai = __shfl(ahv, i, 64);
            p0z = fmaf(ai, sm[i * 64 + lane], p0z);
            p0h = fmaf(ai, sm[2048 + i * 64 + lane], p0h);
        }
        float qz = sm[4096 + lane], qh = sm[4160 + lane];
        float acc = 0.f;
        #pragma unroll
        for (int p = 0; p < 12; ++p) {
            float t = atime[node * 12 + p];
            float z = 1.f / (1.f + __expf(-fmaf(t, qz, p0z)));
            float ht = tanhf(fmaf(t, qh, p0h));
            acc = fmaf(sm[4352 + p] * (1.f - z), ht, acc);
        }
        float h2 = fmaxf(acc, 0.f);
        int k = lane & 31;
        float h3 = sm[6412 + k];
        #pragma unroll
        for (int j = 0; j < 64; ++j) {
            float hj = __shfl(h2, j, 64);
            h3 = fmaf(hj, sm[4364 + j * 32 + k], h3);
        }
        h3 = fmaxf(h3, 0.f);
        float o = (lane < 12) ? sm[6828 + lane] : 0.f;
        #pragma unroll
        for (int kk = 0; kk < 32; ++kk) {
            float h3k = __shfl(h3, kk, 64);
            if (lane < 12) o = fmaf(h3k, sm[6444 + kk * 12 + lane], o);
        }
        if (lane < 12) out[node * 12 + lane] = o;
    }
}

extern "C" void kernel_launch(void* const* d_in, const int* in_sizes, int n_in,
                              void* d_out, int out_size, void* d_ws, size_t ws_size,
                              hipStream_t stream) {
    const float* x1   = (const float*)d_in[0];
    const int*   eidx = (const int*)d_in[1];
    const float* W1   = (const float*)d_in[4];
    const float* b1   = (const float*)d_in[5];
    const float* Wl1  = (const float*)d_in[6];
    const float* bl1  = (const float*)d_in[7];
    const float* att1 = (const float*)d_in[8];
    const float* W2   = (const float*)d_in[9];
    const float* b2   = (const float*)d_in[10];
    const float* Wl2  = (const float*)d_in[11];
    const float* bl2  = (const float*)d_in[12];
    const float* att2 = (const float*)d_in[13];
    const float* lw1  = (const float*)d_in[14];
    const float* lb1  = (const float*)d_in[15];
    const float* lw2  = (const float*)d_in[16];
    const float* lb2  = (const float*)d_in[17];
    (void)n_in; (void)out_size; (void)ws_size;

    int N = in_sizes[0] / 24;
    int E = in_sizes[1] / 2;
    const int* srcp = eidx;
    const int* dstp = eidx + E;

    char* ws = (char*)d_ws;
    size_t off = 0;
    auto alloc = [&](size_t bytes) -> char* {
        char* p = ws + off;
        off += (bytes + 511) & ~(size_t)511;
        return p;
    };
    int*   cnt    = (int*)alloc((size_t)N * 4);
    int*   rowptr = (int*)alloc((size_t)(N + 1) * 4);
    int*   cursor = (int*)alloc((size_t)N * 4);
    float* dinv   = (float*)alloc((size_t)N * 4);
    int*   col    = (int*)alloc((size_t)E * 4);
    float* wgt    = (float*)alloc((size_t)E * 4);
    float* hbuf   = (float*)alloc((size_t)N * 32 * 4);
    float* atime  = (float*)alloc((size_t)N * 12 * 4);
    float* ahh    = (float*)alloc((size_t)N * 32 * 4);
    float* small  = (float*)alloc(4624 * 4);

    zero_ints<<<(N + 255) / 256, 256, 0, stream>>>(cnt, N);
    zero_ints<<<(N + 255) / 256, 256, 0, stream>>>(cursor, N);
    count_edges<<<(E + 255) / 256, 256, 0, stream>>>(dstp, cnt, E);
    scan_dinv<<<1, 1024, 0, stream>>>(cnt, rowptr, dinv, N);
    scatter_edges<<<(E + 255) / 256, 256, 0, stream>>>(srcp, dstp, dinv, rowptr, cursor, col, wgt, E);
    prep_kernel<<<1, 256, 0, stream>>>(W1, b1, Wl1, bl1, att1, W2, b2, Wl2, bl2, att2, small);
    agg1_layer1<<<(N * 32 + 255) / 256, 256, 0, stream>>>(x1, rowptr, col, wgt, dinv, small, hbuf, atime, N);
    agg2<<<(N * 32 + 255) / 256, 256, 0, stream>>>(hbuf, rowptr, col, wgt, dinv, ahh, N);
    layer2_final<<<2048, 256, 0, stream>>>(ahh, atime, small, lw1, lb1, lw2, lb2, (float*)d_out, N);
}

// Round 5
// 266.537 us; speedup vs baseline: 1.6867x; 1.6867x over previous
//
#include <hip/hip_runtime.h>
#include <hip/hip_bf16.h>
#include <math.h>

// ---------------------------------------------------------------------------
// A3T-GCN two-layer, restructured:
//   - H == 0 in every tgcn_cell  =>  R gate dead, cell = (1-Z)*tanh(...)
//   - gcn(x,W,b) = (A_hat x) W + b  =>  propagate features once, fold W@Wl_top
//   - layer2: channels 0..31 period-independent, channel 32 = time;
//     A_hat(time)[:,p] == (A_hat x1)[:, ch 12+p]  => reuse layer-1 propagation
// Round 4 (resubmit after 3x infra failure, same dead pod): layer2_final
// rewritten (LDS float4 weight tiles + ILP, no serial shfl GEMVs); agg edge
// loops unrolled x4 with int2{col,wgt} pairs; shfl scan.
// ---------------------------------------------------------------------------

__global__ void zero2_ints(int* __restrict__ a, int* __restrict__ b, int n) {
    int i = blockIdx.x * blockDim.x + threadIdx.x;
    if (i < n) { a[i] = 0; b[i] = 0; }
}

__global__ void count_edges(const int* __restrict__ dst, int* __restrict__ cnt, int E) {
    int e = blockIdx.x * blockDim.x + threadIdx.x;
    if (e < E) atomicAdd(&cnt[dst[e]], 1);
}

__global__ __launch_bounds__(1024) void scan_dinv(const int* __restrict__ cnt,
                                                  int* __restrict__ rowptr,
                                                  float* __restrict__ dinv, int n) {
    __shared__ int wsum[16];
    __shared__ int carry_s;
    int tid = threadIdx.x, lane = tid & 63, wid = tid >> 6;
    if (tid == 0) carry_s = 0;
    __syncthreads();
    int nchunk = (n + 1023) >> 10;
    for (int ch = 0; ch < nchunk; ++ch) {
        int i = (ch << 10) + tid;
        int v = (i < n) ? cnt[i] : 0;
        if (i < n) dinv[i] = rsqrtf((float)v + 1.0f);
        int orig = v;
        #pragma unroll
        for (int off = 1; off < 64; off <<= 1) {
            int t = __shfl_up(v, off, 64);
            if (lane >= off) v += t;
        }
        if (lane == 63) wsum[wid] = v;
        __syncthreads();
        if (wid == 0) {
            int s = (lane < 16) ? wsum[lane] : 0;
            #pragma unroll
            for (int off = 1; off < 16; off <<= 1) {
                int t = __shfl_up(s, off, 64);
                if (lane >= off) s += t;
            }
            if (lane < 16) wsum[lane] = s;  // inclusive over waves
        }
        __syncthreads();
        int wpre = (wid == 0) ? 0 : wsum[wid - 1];
        int total = wsum[15];
        int excl = carry_s + wpre + v - orig;
        if (i < n) rowptr[i] = excl;
        __syncthreads();
        if (tid == 0) carry_s += total;
        __syncthreads();
    }
    if (tid == 0) rowptr[n] = carry_s;
}

__global__ void scatter_edges(const int* __restrict__ src, const int* __restrict__ dst,
                              const float* __restrict__ dinv, const int* __restrict__ rowptr,
                              int* __restrict__ cursor, int2* __restrict__ cw, int E) {
    int e = blockIdx.x * blockDim.x + threadIdx.x;
    if (e >= E) return;
    int s = src[e], d = dst[e];
    int pos = atomicAdd(&cursor[d], 1);
    int idx = rowptr[d] + pos;
    cw[idx] = make_int2(s, __float_as_int(dinv[s] * dinv[d]));
}

// small[] layout (floats):
//   [0:32)a0z [32:64)a1z [64:96)c1z [96:128)a0h [128:160)a1h [160:192)c1h [192:204)probs1
//   [256:2304) M2z   [2304:4352) M2h
//   [4352:4416) q2z [4416:4480) q2h [4480:4544) c2z [4544:4608) c2h [4608:4620) probs2
__global__ __launch_bounds__(256) void prep_kernel(
    const float* __restrict__ W1, const float* __restrict__ b1,
    const float* __restrict__ Wl1, const float* __restrict__ bl1,
    const float* __restrict__ att1,
    const float* __restrict__ W2, const float* __restrict__ b2,
    const float* __restrict__ Wl2, const float* __restrict__ bl2,
    const float* __restrict__ att2, float* __restrict__ small) {
    int tid = threadIdx.x;
    for (int t = tid; t < 192; t += blockDim.x) {
        int which = t >> 5, hh = t & 31;
        int g = (which < 3) ? 0 : 2;
        int kind = which % 3;  // 0:a0 1:a1 2:c
        const float* Wl = Wl1 + g * 64 * 32;
        float s = 0.f;
        if (kind < 2) {
            const float* Wr = W1 + g * 2 * 32 + kind * 32;
            for (int k = 0; k < 32; ++k) s += Wr[k] * Wl[k * 32 + hh];
        } else {
            const float* br = b1 + g * 32;
            for (int k = 0; k < 32; ++k) s += br[k] * Wl[k * 32 + hh];
            s += bl1[g * 32 + hh];
        }
        small[t] = s;
    }
    for (int t = tid; t < 4096; t += blockDim.x) {
        int gg = t >> 11;
        int rem = t & 2047;
        int i = rem >> 6, j = rem & 63;
        int g = gg ? 2 : 0;
        const float* Wl = Wl2 + g * 128 * 64;
        const float* Wr = W2 + g * 33 * 64 + i * 64;
        float s = 0.f;
        for (int k = 0; k < 64; ++k) s += Wr[k] * Wl[k * 64 + j];
        small[256 + gg * 2048 + i * 64 + j] = s;
    }
    for (int t = tid; t < 256; t += blockDim.x) {
        int which = t >> 6, j = t & 63;
        int g = (which == 0 || which == 2) ? 0 : 2;
        const float* Wl = Wl2 + g * 128 * 64;
        float s = 0.f;
        if (which < 2) {
            const float* Wr = W2 + g * 33 * 64 + 32 * 64;
            for (int k = 0; k < 64; ++k) s += Wr[k] * Wl[k * 64 + j];
        } else {
            const float* br = b2 + g * 64;
            for (int k = 0; k < 64; ++k) s += br[k] * Wl[k * 64 + j];
            s += bl2[g * 64 + j];
        }
        small[4352 + which * 64 + j] = s;
    }
    if (tid == 0) {
        float mx = att1[0];
        for (int p = 1; p < 12; ++p) mx = fmaxf(mx, att1[p]);
        float e[12], sm = 0.f;
        for (int p = 0; p < 12; ++p) { e[p] = expf(att1[p] - mx); sm += e[p]; }
        for (int p = 0; p < 12; ++p) small[192 + p] = e[p] / sm;
        mx = att2[0];
        for (int p = 1; p < 12; ++p) mx = fmaxf(mx, att2[p]);
        sm = 0.f;
        for (int p = 0; p < 12; ++p) { e[p] = expf(att2[p] - mx); sm += e[p]; }
        for (int p = 0; p < 12; ++p) small[4608 + p] = e[p] / sm;
    }
}

// One 32-lane group per node. Lanes 0..23 aggregate A_hat x1 (24 ch);
// edge loop unrolled x4 for memory-level parallelism.
__global__ __launch_bounds__(256) void agg1_layer1(
    const float* __restrict__ X, const int* __restrict__ rowptr,
    const int2* __restrict__ cw, const float* __restrict__ dinv,
    const float* __restrict__ small,
    float* __restrict__ hout, float* __restrict__ atime, int n) {
    int lane = threadIdx.x & 31;
    int node = (blockIdx.x * blockDim.x + threadIdx.x) >> 5;
    if (node >= n) return;
    int beg = rowptr[node], end = rowptr[node + 1];
    float acc = 0.f;
    if (lane < 24) {
        float dn = dinv[node];
        acc = dn * dn * X[node * 24 + lane];
        float a0 = 0.f, a1 = 0.f, a2 = 0.f, a3 = 0.f;
        int j = beg;
        for (; j + 4 <= end; j += 4) {
            int2 c0 = cw[j], c1 = cw[j + 1], c2 = cw[j + 2], c3 = cw[j + 3];
            a0 = fmaf(__int_as_float(c0.y), X[c0.x * 24 + lane], a0);
            a1 = fmaf(__int_as_float(c1.y), X[c1.x * 24 + lane], a1);
            a2 = fmaf(__int_as_float(c2.y), X[c2.x * 24 + lane], a2);
            a3 = fmaf(__int_as_float(c3.y), X[c3.x * 24 + lane], a3);
        }
        for (; j < end; ++j) {
            int2 c = cw[j];
            acc = fmaf(__int_as_float(c.y), X[c.x * 24 + lane], acc);
        }
        acc += (a0 + a1) + (a2 + a3);
    }
    if (lane >= 12 && lane < 24) atime[node * 12 + lane - 12] = acc;
    float a0z = small[lane], a1z = small[32 + lane], c1z = small[64 + lane];
    float a0h = small[96 + lane], a1h = small[128 + lane], c1h = small[160 + lane];
    float hs = 0.f;
    #pragma unroll
    for (int p = 0; p < 12; ++p) {
        float x0 = __shfl(acc, p, 32);
        float x1 = __shfl(acc, 12 + p, 32);
        float z = 1.f / (1.f + __expf(-fmaf(x0, a0z, fmaf(x1, a1z, c1z))));
        float ht = tanhf(fmaf(x0, a0h, fmaf(x1, a1h, c1h)));
        hs = fmaf(small[192 + p] * (1.f - z), ht, hs);
    }
    hout[node * 32 + lane] = fmaxf(hs, 0.f);
}

// A_hat applied to h (32 channels) -> ahh ; edge loop unrolled x4.
__global__ __launch_bounds__(256) void agg2(
    const float* __restrict__ h, const int* __restrict__ rowptr,
    const int2* __restrict__ cw, const float* __restrict__ dinv,
    float* __restrict__ ahh, int n) {
    int lane = threadIdx.x & 31;
    int node = (blockIdx.x * blockDim.x + threadIdx.x) >> 5;
    if (node >= n) return;
    float dn = dinv[node];
    float acc = dn * dn * h[node * 32 + lane];
    int beg = rowptr[node], end = rowptr[node + 1];
    float a0 = 0.f, a1 = 0.f, a2 = 0.f, a3 = 0.f;
    int j = beg;
    for (; j + 4 <= end; j += 4) {
        int2 c0 = cw[j], c1 = cw[j + 1], c2 = cw[j + 2], c3 = cw[j + 3];
        a0 = fmaf(__int_as_float(c0.y), h[c0.x * 32 + lane], a0);
        a1 = fmaf(__int_as_float(c1.y), h[c1.x * 32 + lane], a1);
        a2 = fmaf(__int_as_float(c2.y), h[c2.x * 32 + lane], a2);
        a3 = fmaf(__int_as_float(c3.y), h[c3.x * 32 + lane], a3);
    }
    for (; j < end; ++j) {
        int2 c = cw[j];
        acc = fmaf(__int_as_float(c.y), h[c.x * 32 + lane], acc);
    }
    acc += (a0 + a1) + (a2 + a3);
    ahh[node * 32 + lane] = acc;
}

// One 64-lane wave per node; lane = layer-2 channel j.
// Weights in LDS as interleaved float4 tiles; ahh row via wave-uniform float4
// global loads; h2 bounced through per-wave LDS buffer (no block barrier).
__global__ __launch_bounds__(256, 4) void layer2_final(
    const float* __restrict__ ahh, const float* __restrict__ atime,
    const float* __restrict__ small, const float* __restrict__ lw1,
    const float* __restrict__ lb1, const float* __restrict__ lw2,
    const float* __restrict__ lb2, float* __restrict__ out, int n) {
    // wqs[k2*64+j] = {Mz[2k2][j], Mh[2k2][j], Mz[2k2+1][j], Mh[2k2+1][j]}
    __shared__ __align__(16) float4 wqs[1024];          // 16 KB
    __shared__ float s_q[256];                           // qz|qh|cz|ch
    __shared__ float s_pr[16];
    __shared__ __align__(16) float s_lw1[2048];          // [j][k] 64x32
    __shared__ float s_lb1[32];
    __shared__ float s_lw2[512];                         // [k][p] 32x16 (padded)
    __shared__ float s_lb2[16];
    __shared__ __align__(16) float4 h2b[4][16];          // per-wave h2 scratch

    for (int t = threadIdx.x; t < 4096; t += 256) {
        int s = t & 3, j = (t >> 2) & 63, k2 = t >> 8;
        int k = 2 * k2 + (s >> 1), zh = s & 1;
        ((float*)wqs)[t] = small[256 + zh * 2048 + k * 64 + j];
    }
    {
        int t = threadIdx.x;
        s_q[t] = small[4352 + t];                        // qz,qh,cz,ch
        if (t < 16) s_pr[t] = (t < 12) ? small[4608 + t] : 0.f;
        if (t < 32) s_lb1[t] = lb1[t];
        if (t < 16) s_lb2[t] = (t < 12) ? lb2[t] : 0.f;
    }
    for (int t = threadIdx.x; t < 2048; t += 256) s_lw1[t] = lw1[t];
    for (int t = threadIdx.x; t < 512; t += 256) {
        int k = t >> 4, p = t & 15;
        s_lw2[t] = (p < 12) ? lw2[k * 12 + p] : 0.f;
    }
    __syncthreads();

    int lane = threadIdx.x & 63;
    int wid = threadIdx.x >> 6;
    int totalw = gridDim.x * 4;
    for (int node = blockIdx.x * 4 + wid; node < n; node += totalw) {
        const float4* arow = (const float4*)(ahh + (size_t)node * 32);
        const float4* trow = (const float4*)(atime + (size_t)node * 12);
        int j = lane;
        float p0z = s_q[128 + j], p0h = s_q[192 + j];
        #pragma unroll
        for (int c = 0; c < 8; ++c) {
            float4 av = arow[c];
            float4 w0 = wqs[(2 * c) * 64 + j];
            float4 w1 = wqs[(2 * c + 1) * 64 + j];
            p0z = fmaf(av.x, w0.x, p0z); p0h = fmaf(av.x, w0.y, p0h);
            p0z = fmaf(av.y, w0.z, p0z); p0h = fmaf(av.y, w0.w, p0h);
            p0z = fmaf(av.z, w1.x, p0z); p0h = fmaf(av.z, w1.y, p0h);
            p0z = fmaf(av.w, w1.z, p0z); p0h = fmaf(av.w, w1.w, p0h);
        }
        float4 tA = trow[0], tB = trow[1], tC = trow[2];
        float tt[12] = {tA.x, tA.y, tA.z, tA.w, tB.x, tB.y, tB.z, tB.w,
                        tC.x, tC.y, tC.z, tC.w};
        float qz = s_q[j], qh = s_q[64 + j];
        float acc = 0.f;
        #pragma unroll
        for (int p = 0; p < 12; ++p) {
            float t = tt[p];
            float ez = __expf(-fmaf(t, qz, p0z));
            float omz = ez * __builtin_amdgcn_rcpf(1.f + ez);       // 1 - sigmoid
            float eh = __expf(-2.f * fmaf(t, qh, p0h));
            float ht = (1.f - eh) * __builtin_amdgcn_rcpf(1.f + eh); // tanh
            acc = fmaf(s_pr[p] * omz, ht, acc);
        }
        float h2 = fmaxf(acc, 0.f);
        ((float*)&h2b[wid][0])[lane] = h2;
        asm volatile("s_waitcnt lgkmcnt(0)" ::: "memory");
        int k = lane & 31, half = lane >> 5;
        float h3 = half ? 0.f : s_lb1[k];
        const float4* hrow = &h2b[wid][half * 8];
        #pragma unroll
        for (int c = 0; c < 8; ++c) {
            float4 hv = hrow[c];
            int jb = half * 32 + c * 4;
            h3 = fmaf(hv.x, s_lw1[(jb + 0) * 32 + k], h3);
            h3 = fmaf(hv.y, s_lw1[(jb + 1) * 32 + k], h3);
            h3 = fmaf(hv.z, s_lw1[(jb + 2) * 32 + k], h3);
            h3 = fmaf(hv.w, s_lw1[(jb + 3) * 32 + k], h3);
        }
        h3 += __shfl_xor(h3, 32, 64);
        h3 = fmaxf(h3, 0.f);
        int p = lane & 15, q = lane >> 4;
        float o = (q == 0) ? s_lb2[p] : 0.f;
        #pragma unroll
        for (int i = 0; i < 8; ++i) {
            int kk = q * 8 + i;
            float h3k = __shfl(h3, kk, 64);
            o = fmaf(h3k, s_lw2[kk * 16 + p], o);
        }
        o += __shfl_xor(o, 16, 64);
        o += __shfl_xor(o, 32, 64);
        if (lane < 12) out[(size_t)node * 12 + lane] = o;
    }
}

extern "C" void kernel_launch(void* const* d_in, const int* in_sizes, int n_in,
                              void* d_out, int out_size, void* d_ws, size_t ws_size,
                              hipStream_t stream) {
    const float* x1   = (const float*)d_in[0];
    const int*   eidx = (const int*)d_in[1];
    const float* W1   = (const float*)d_in[4];
    const float* b1   = (const float*)d_in[5];
    const float* Wl1  = (const float*)d_in[6];
    const float* bl1  = (const float*)d_in[7];
    const float* att1 = (const float*)d_in[8];
    const float* W2   = (const float*)d_in[9];
    const float* b2   = (const float*)d_in[10];
    const float* Wl2  = (const float*)d_in[11];
    const float* bl2  = (const float*)d_in[12];
    const float* att2 = (const float*)d_in[13];
    const float* lw1  = (const float*)d_in[14];
    const float* lb1  = (const float*)d_in[15];
    const float* lw2  = (const float*)d_in[16];
    const float* lb2  = (const float*)d_in[17];
    (void)n_in; (void)out_size; (void)ws_size;

    int N = in_sizes[0] / 24;
    int E = in_sizes[1] / 2;
    const int* srcp = eidx;
    const int* dstp = eidx + E;

    char* ws = (char*)d_ws;
    size_t off = 0;
    auto alloc = [&](size_t bytes) -> char* {
        char* p = ws + off;
        off += (bytes + 511) & ~(size_t)511;
        return p;
    };
    int*   cnt    = (int*)alloc((size_t)N * 4);
    int*   rowptr = (int*)alloc((size_t)(N + 1) * 4);
    int*   cursor = (int*)alloc((size_t)N * 4);
    float* dinv   = (float*)alloc((size_t)N * 4);
    int2*  cw     = (int2*)alloc((size_t)E * 8);
    float* hbuf   = (float*)alloc((size_t)N * 32 * 4);
    float* atime  = (float*)alloc((size_t)N * 12 * 4);
    float* ahh    = (float*)alloc((size_t)N * 32 * 4);
    float* small  = (float*)alloc(4624 * 4);

    prep_kernel<<<1, 256, 0, stream>>>(W1, b1, Wl1, bl1, att1, W2, b2, Wl2, bl2, att2, small);
    zero2_ints<<<(N + 255) / 256, 256, 0, stream>>>(cnt, cursor, N);
    count_edges<<<(E + 255) / 256, 256, 0, stream>>>(dstp, cnt, E);
    scan_dinv<<<1, 1024, 0, stream>>>(cnt, rowptr, dinv, N);
    scatter_edges<<<(E + 255) / 256, 256, 0, stream>>>(srcp, dstp, dinv, rowptr, cursor, cw, E);
    agg1_layer1<<<(N * 32 + 255) / 256, 256, 0, stream>>>(x1, rowptr, cw, dinv, small, hbuf, atime, N);
    agg2<<<(N * 32 + 255) / 256, 256, 0, stream>>>(hbuf, rowptr, cw, dinv, ahh, N);
    layer2_final<<<2048, 256, 0, stream>>>(ahh, atime, small, lw1, lb1, lw2, lb2, (float*)d_out, N);
}

// Round 6
// 219.711 us; speedup vs baseline: 2.0462x; 1.2131x over previous
//
#include <hip/hip_runtime.h>
#include <hip/hip_bf16.h>
#include <math.h>

// ---------------------------------------------------------------------------
// A3T-GCN two-layer, restructured (see round-1 notes):
//   - H == 0 => R gate dead, cell = (1-Z)*tanh(...)
//   - A_hat commutes with W => one propagation per layer, folded gate matrices
//   - layer2 time channel reuses layer-1 propagation (rank-1 per period)
// Round 6: replace single-block chained scan_dinv (55.9 us, occupancy 0.16%)
// with 3-kernel parallel scan (blocksum -> boffs -> write). Rest unchanged.
// ---------------------------------------------------------------------------

__global__ void zero2_ints(int* __restrict__ a, int* __restrict__ b, int n) {
    int i = blockIdx.x * blockDim.x + threadIdx.x;
    if (i < n) { a[i] = 0; b[i] = 0; }
}

__global__ void count_edges(const int* __restrict__ dst, int* __restrict__ cnt, int E) {
    int e = blockIdx.x * blockDim.x + threadIdx.x;
    if (e < E) atomicAdd(&cnt[dst[e]], 1);
}

// --- parallel exclusive scan of cnt -> rowptr, plus dinv ------------------
// A: each block covers 1024 elems (256 thr x int4): block total + dinv.
__global__ __launch_bounds__(256) void scan_blocksum(
    const int* __restrict__ cnt, float* __restrict__ dinv,
    int* __restrict__ bsum, int n) {
    int base = blockIdx.x * 1024 + threadIdx.x * 4;
    int s = 0;
    if (base + 3 < n) {
        int4 v = *(const int4*)(cnt + base);
        dinv[base + 0] = rsqrtf((float)v.x + 1.f);
        dinv[base + 1] = rsqrtf((float)v.y + 1.f);
        dinv[base + 2] = rsqrtf((float)v.z + 1.f);
        dinv[base + 3] = rsqrtf((float)v.w + 1.f);
        s = v.x + v.y + v.z + v.w;
    } else {
        for (int k = 0; k < 4; ++k)
            if (base + k < n) {
                int v = cnt[base + k];
                dinv[base + k] = rsqrtf((float)v + 1.f);
                s += v;
            }
    }
    #pragma unroll
    for (int off = 32; off > 0; off >>= 1) s += __shfl_down(s, off, 64);
    __shared__ int ws[4];
    int lane = threadIdx.x & 63, wid = threadIdx.x >> 6;
    if (lane == 0) ws[wid] = s;
    __syncthreads();
    if (threadIdx.x == 0) bsum[blockIdx.x] = ws[0] + ws[1] + ws[2] + ws[3];
}

// B: one wave scans nb block sums (exclusive) and writes rowptr[n].
__global__ void scan_boffs(const int* __restrict__ bsum, int* __restrict__ boffs,
                           int* __restrict__ rowptr, int nb, int n) {
    int lane = threadIdx.x;
    int carry = 0;
    for (int base = 0; base < nb; base += 64) {
        int i = base + lane;
        int v = (i < nb) ? bsum[i] : 0;
        int orig = v;
        #pragma unroll
        for (int off = 1; off < 64; off <<= 1) {
            int t = __shfl_up(v, off, 64);
            if (lane >= off) v += t;
        }
        if (i < nb) boffs[i] = carry + v - orig;  // exclusive
        carry += __shfl(v, 63, 64);
    }
    if (lane == 0) rowptr[n] = carry;
}

// C: each block rescans its 1024 elems, adds its offset, writes rowptr.
__global__ __launch_bounds__(256) void scan_write(
    const int* __restrict__ cnt, const int* __restrict__ boffs,
    int* __restrict__ rowptr, int n) {
    int base = blockIdx.x * 1024 + threadIdx.x * 4;
    int4 v = make_int4(0, 0, 0, 0);
    if (base + 3 < n) {
        v = *(const int4*)(cnt + base);
    } else {
        if (base + 0 < n) v.x = cnt[base + 0];
        if (base + 1 < n) v.y = cnt[base + 1];
        if (base + 2 < n) v.z = cnt[base + 2];
        if (base + 3 < n) v.w = cnt[base + 3];
    }
    int t0 = v.x, t1 = t0 + v.y, t2 = t1 + v.z, t3 = t2 + v.w;  // inclusive
    int lane = threadIdx.x & 63, wid = threadIdx.x >> 6;
    int sc = t3;
    #pragma unroll
    for (int off = 1; off < 64; off <<= 1) {
        int t = __shfl_up(sc, off, 64);
        if (lane >= off) sc += t;
    }
    __shared__ int ws[4];
    if (lane == 63) ws[wid] = sc;
    __syncthreads();
    int woff = 0;
    for (int w = 0; w < wid; ++w) woff += ws[w];
    int off0 = boffs[blockIdx.x] + woff + sc - t3;  // exclusive at base
    if (base + 3 < n) {
        *(int4*)(rowptr + base) = make_int4(off0, off0 + t0, off0 + t1, off0 + t2);
    } else {
        if (base + 0 < n) rowptr[base + 0] = off0;
        if (base + 1 < n) rowptr[base + 1] = off0 + t0;
        if (base + 2 < n) rowptr[base + 2] = off0 + t1;
        if (base + 3 < n) rowptr[base + 3] = off0 + t2;
    }
}

__global__ void scatter_edges(const int* __restrict__ src, const int* __restrict__ dst,
                              const float* __restrict__ dinv, const int* __restrict__ rowptr,
                              int* __restrict__ cursor, int2* __restrict__ cw, int E) {
    int e = blockIdx.x * blockDim.x + threadIdx.x;
    if (e >= E) return;
    int s = src[e], d = dst[e];
    int pos = atomicAdd(&cursor[d], 1);
    int idx = rowptr[d] + pos;
    cw[idx] = make_int2(s, __float_as_int(dinv[s] * dinv[d]));
}

// small[] layout (floats):
//   [0:32)a0z [32:64)a1z [64:96)c1z [96:128)a0h [128:160)a1h [160:192)c1h [192:204)probs1
//   [256:2304) M2z   [2304:4352) M2h
//   [4352:4416) q2z [4416:4480) q2h [4480:4544) c2z [4544:4608) c2h [4608:4620) probs2
__global__ __launch_bounds__(256) void prep_kernel(
    const float* __restrict__ W1, const float* __restrict__ b1,
    const float* __restrict__ Wl1, const float* __restrict__ bl1,
    const float* __restrict__ att1,
    const float* __restrict__ W2, const float* __restrict__ b2,
    const float* __restrict__ Wl2, const float* __restrict__ bl2,
    const float* __restrict__ att2, float* __restrict__ small) {
    int tid = threadIdx.x;
    for (int t = tid; t < 192; t += blockDim.x) {
        int which = t >> 5, hh = t & 31;
        int g = (which < 3) ? 0 : 2;
        int kind = which % 3;  // 0:a0 1:a1 2:c
        const float* Wl = Wl1 + g * 64 * 32;
        float s = 0.f;
        if (kind < 2) {
            const float* Wr = W1 + g * 2 * 32 + kind * 32;
            for (int k = 0; k < 32; ++k) s += Wr[k] * Wl[k * 32 + hh];
        } else {
            const float* br = b1 + g * 32;
            for (int k = 0; k < 32; ++k) s += br[k] * Wl[k * 32 + hh];
            s += bl1[g * 32 + hh];
        }
        small[t] = s;
    }
    for (int t = tid; t < 4096; t += blockDim.x) {
        int gg = t >> 11;
        int rem = t & 2047;
        int i = rem >> 6, j = rem & 63;
        int g = gg ? 2 : 0;
        const float* Wl = Wl2 + g * 128 * 64;
        const float* Wr = W2 + g * 33 * 64 + i * 64;
        float s = 0.f;
        for (int k = 0; k < 64; ++k) s += Wr[k] * Wl[k * 64 + j];
        small[256 + gg * 2048 + i * 64 + j] = s;
    }
    for (int t = tid; t < 256; t += blockDim.x) {
        int which = t >> 6, j = t & 63;
        int g = (which == 0 || which == 2) ? 0 : 2;
        const float* Wl = Wl2 + g * 128 * 64;
        float s = 0.f;
        if (which < 2) {
            const float* Wr = W2 + g * 33 * 64 + 32 * 64;
            for (int k = 0; k < 64; ++k) s += Wr[k] * Wl[k * 64 + j];
        } else {
            const float* br = b2 + g * 64;
            for (int k = 0; k < 64; ++k) s += br[k] * Wl[k * 64 + j];
            s += bl2[g * 64 + j];
        }
        small[4352 + which * 64 + j] = s;
    }
    if (tid == 0) {
        float mx = att1[0];
        for (int p = 1; p < 12; ++p) mx = fmaxf(mx, att1[p]);
        float e[12], sm = 0.f;
        for (int p = 0; p < 12; ++p) { e[p] = expf(att1[p] - mx); sm += e[p]; }
        for (int p = 0; p < 12; ++p) small[192 + p] = e[p] / sm;
        mx = att2[0];
        for (int p = 1; p < 12; ++p) mx = fmaxf(mx, att2[p]);
        sm = 0.f;
        for (int p = 0; p < 12; ++p) { e[p] = expf(att2[p] - mx); sm += e[p]; }
        for (int p = 0; p < 12; ++p) small[4608 + p] = e[p] / sm;
    }
}

// One 32-lane group per node. Lanes 0..23 aggregate A_hat x1 (24 ch);
// edge loop unrolled x4 for memory-level parallelism.
__global__ __launch_bounds__(256) void agg1_layer1(
    const float* __restrict__ X, const int* __restrict__ rowptr,
    const int2* __restrict__ cw, const float* __restrict__ dinv,
    const float* __restrict__ small,
    float* __restrict__ hout, float* __restrict__ atime, int n) {
    int lane = threadIdx.x & 31;
    int node = (blockIdx.x * blockDim.x + threadIdx.x) >> 5;
    if (node >= n) return;
    int beg = rowptr[node], end = rowptr[node + 1];
    float acc = 0.f;
    if (lane < 24) {
        float dn = dinv[node];
        acc = dn * dn * X[node * 24 + lane];
        float a0 = 0.f, a1 = 0.f, a2 = 0.f, a3 = 0.f;
        int j = beg;
        for (; j + 4 <= end; j += 4) {
            int2 c0 = cw[j], c1 = cw[j + 1], c2 = cw[j + 2], c3 = cw[j + 3];
            a0 = fmaf(__int_as_float(c0.y), X[c0.x * 24 + lane], a0);
            a1 = fmaf(__int_as_float(c1.y), X[c1.x * 24 + lane], a1);
            a2 = fmaf(__int_as_float(c2.y), X[c2.x * 24 + lane], a2);
            a3 = fmaf(__int_as_float(c3.y), X[c3.x * 24 + lane], a3);
        }
        for (; j < end; ++j) {
            int2 c = cw[j];
            acc = fmaf(__int_as_float(c.y), X[c.x * 24 + lane], acc);
        }
        acc += (a0 + a1) + (a2 + a3);
    }
    if (lane >= 12 && lane < 24) atime[node * 12 + lane - 12] = acc;
    float a0z = small[lane], a1z = small[32 + lane], c1z = small[64 + lane];
    float a0h = small[96 + lane], a1h = small[128 + lane], c1h = small[160 + lane];
    float hs = 0.f;
    #pragma unroll
    for (int p = 0; p < 12; ++p) {
        float x0 = __shfl(acc, p, 32);
        float x1 = __shfl(acc, 12 + p, 32);
        float z = 1.f / (1.f + __expf(-fmaf(x0, a0z, fmaf(x1, a1z, c1z))));
        float ht = tanhf(fmaf(x0, a0h, fmaf(x1, a1h, c1h)));
        hs = fmaf(small[192 + p] * (1.f - z), ht, hs);
    }
    hout[node * 32 + lane] = fmaxf(hs, 0.f);
}

// A_hat applied to h (32 channels) -> ahh ; edge loop unrolled x4.
__global__ __launch_bounds__(256) void agg2(
    const float* __restrict__ h, const int* __restrict__ rowptr,
    const int2* __restrict__ cw, const float* __restrict__ dinv,
    float* __restrict__ ahh, int n) {
    int lane = threadIdx.x & 31;
    int node = (blockIdx.x * blockDim.x + threadIdx.x) >> 5;
    if (node >= n) return;
    float dn = dinv[node];
    float acc = dn * dn * h[node * 32 + lane];
    int beg = rowptr[node], end = rowptr[node + 1];
    float a0 = 0.f, a1 = 0.f, a2 = 0.f, a3 = 0.f;
    int j = beg;
    for (; j + 4 <= end; j += 4) {
        int2 c0 = cw[j], c1 = cw[j + 1], c2 = cw[j + 2], c3 = cw[j + 3];
        a0 = fmaf(__int_as_float(c0.y), h[c0.x * 32 + lane], a0);
        a1 = fmaf(__int_as_float(c1.y), h[c1.x * 32 + lane], a1);
        a2 = fmaf(__int_as_float(c2.y), h[c2.x * 32 + lane], a2);
        a3 = fmaf(__int_as_float(c3.y), h[c3.x * 32 + lane], a3);
    }
    for (; j < end; ++j) {
        int2 c = cw[j];
        acc = fmaf(__int_as_float(c.y), h[c.x * 32 + lane], acc);
    }
    acc += (a0 + a1) + (a2 + a3);
    ahh[node * 32 + lane] = acc;
}

// One 64-lane wave per node; lane = layer-2 channel j.
// Weights in LDS as interleaved float4 tiles; ahh row via wave-uniform float4
// global loads; h2 bounced through per-wave LDS buffer (no block barrier).
__global__ __launch_bounds__(256, 4) void layer2_final(
    const float* __restrict__ ahh, const float* __restrict__ atime,
    const float* __restrict__ small, const float* __restrict__ lw1,
    const float* __restrict__ lb1, const float* __restrict__ lw2,
    const float* __restrict__ lb2, float* __restrict__ out, int n) {
    // wqs[k2*64+j] = {Mz[2k2][j], Mh[2k2][j], Mz[2k2+1][j], Mh[2k2+1][j]}
    __shared__ __align__(16) float4 wqs[1024];          // 16 KB
    __shared__ float s_q[256];                           // qz|qh|cz|ch
    __shared__ float s_pr[16];
    __shared__ __align__(16) float s_lw1[2048];          // [j][k] 64x32
    __shared__ float s_lb1[32];
    __shared__ float s_lw2[512];                         // [k][p] 32x16 (padded)
    __shared__ float s_lb2[16];
    __shared__ __align__(16) float4 h2b[4][16];          // per-wave h2 scratch

    for (int t = threadIdx.x; t < 4096; t += 256) {
        int s = t & 3, j = (t >> 2) & 63, k2 = t >> 8;
        int k = 2 * k2 + (s >> 1), zh = s & 1;
        ((float*)wqs)[t] = small[256 + zh * 2048 + k * 64 + j];
    }
    {
        int t = threadIdx.x;
        s_q[t] = small[4352 + t];                        // qz,qh,cz,ch
        if (t < 16) s_pr[t] = (t < 12) ? small[4608 + t] : 0.f;
        if (t < 32) s_lb1[t] = lb1[t];
        if (t < 16) s_lb2[t] = (t < 12) ? lb2[t] : 0.f;
    }
    for (int t = threadIdx.x; t < 2048; t += 256) s_lw1[t] = lw1[t];
    for (int t = threadIdx.x; t < 512; t += 256) {
        int k = t >> 4, p = t & 15;
        s_lw2[t] = (p < 12) ? lw2[k * 12 + p] : 0.f;
    }
    __syncthreads();

    int lane = threadIdx.x & 63;
    int wid = threadIdx.x >> 6;
    int totalw = gridDim.x * 4;
    for (int node = blockIdx.x * 4 + wid; node < n; node += totalw) {
        const float4* arow = (const float4*)(ahh + (size_t)node * 32);
        const float4* trow = (const float4*)(atime + (size_t)node * 12);
        int j = lane;
        float p0z = s_q[128 + j], p0h = s_q[192 + j];
        #pragma unroll
        for (int c = 0; c < 8; ++c) {
            float4 av = arow[c];
            float4 w0 = wqs[(2 * c) * 64 + j];
            float4 w1 = wqs[(2 * c + 1) * 64 + j];
            p0z = fmaf(av.x, w0.x, p0z); p0h = fmaf(av.x, w0.y, p0h);
            p0z = fmaf(av.y, w0.z, p0z); p0h = fmaf(av.y, w0.w, p0h);
            p0z = fmaf(av.z, w1.x, p0z); p0h = fmaf(av.z, w1.y, p0h);
            p0z = fmaf(av.w, w1.z, p0z); p0h = fmaf(av.w, w1.w, p0h);
        }
        float4 tA = trow[0], tB = trow[1], tC = trow[2];
        float tt[12] = {tA.x, tA.y, tA.z, tA.w, tB.x, tB.y, tB.z, tB.w,
                        tC.x, tC.y, tC.z, tC.w};
        float qz = s_q[j], qh = s_q[64 + j];
        float acc = 0.f;
        #pragma unroll
        for (int p = 0; p < 12; ++p) {
            float t = tt[p];
            float ez = __expf(-fmaf(t, qz, p0z));
            float omz = ez * __builtin_amdgcn_rcpf(1.f + ez);       // 1 - sigmoid
            float eh = __expf(-2.f * fmaf(t, qh, p0h));
            float ht = (1.f - eh) * __builtin_amdgcn_rcpf(1.f + eh); // tanh
            acc = fmaf(s_pr[p] * omz, ht, acc);
        }
        float h2 = fmaxf(acc, 0.f);
        ((float*)&h2b[wid][0])[lane] = h2;
        asm volatile("s_waitcnt lgkmcnt(0)" ::: "memory");
        int k = lane & 31, half = lane >> 5;
        float h3 = half ? 0.f : s_lb1[k];
        const float4* hrow = &h2b[wid][half * 8];
        #pragma unroll
        for (int c = 0; c < 8; ++c) {
            float4 hv = hrow[c];
            int jb = half * 32 + c * 4;
            h3 = fmaf(hv.x, s_lw1[(jb + 0) * 32 + k], h3);
            h3 = fmaf(hv.y, s_lw1[(jb + 1) * 32 + k], h3);
            h3 = fmaf(hv.z, s_lw1[(jb + 2) * 32 + k], h3);
            h3 = fmaf(hv.w, s_lw1[(jb + 3) * 32 + k], h3);
        }
        h3 += __shfl_xor(h3, 32, 64);
        h3 = fmaxf(h3, 0.f);
        int p = lane & 15, q = lane >> 4;
        float o = (q == 0) ? s_lb2[p] : 0.f;
        #pragma unroll
        for (int i = 0; i < 8; ++i) {
            int kk = q * 8 + i;
            float h3k = __shfl(h3, kk, 64);
            o = fmaf(h3k, s_lw2[kk * 16 + p], o);
        }
        o += __shfl_xor(o, 16, 64);
        o += __shfl_xor(o, 32, 64);
        if (lane < 12) out[(size_t)node * 12 + lane] = o;
    }
}

extern "C" void kernel_launch(void* const* d_in, const int* in_sizes, int n_in,
                              void* d_out, int out_size, void* d_ws, size_t ws_size,
                              hipStream_t stream) {
    const float* x1   = (const float*)d_in[0];
    const int*   eidx = (const int*)d_in[1];
    const float* W1   = (const float*)d_in[4];
    const float* b1   = (const float*)d_in[5];
    const float* Wl1  = (const float*)d_in[6];
    const float* bl1  = (const float*)d_in[7];
    const float* att1 = (const float*)d_in[8];
    const float* W2   = (const float*)d_in[9];
    const float* b2   = (const float*)d_in[10];
    const float* Wl2  = (const float*)d_in[11];
    const float* bl2  = (const float*)d_in[12];
    const float* att2 = (const float*)d_in[13];
    const float* lw1  = (const float*)d_in[14];
    const float* lb1  = (const float*)d_in[15];
    const float* lw2  = (const float*)d_in[16];
    const float* lb2  = (const float*)d_in[17];
    (void)n_in; (void)out_size; (void)ws_size;

    int N = in_sizes[0] / 24;
    int E = in_sizes[1] / 2;
    const int* srcp = eidx;
    const int* dstp = eidx + E;
    int nb = (N + 1023) / 1024;

    char* ws = (char*)d_ws;
    size_t off = 0;
    auto alloc = [&](size_t bytes) -> char* {
        char* p = ws + off;
        off += (bytes + 511) & ~(size_t)511;
        return p;
    };
    int*   cnt    = (int*)alloc((size_t)N * 4);
    int*   rowptr = (int*)alloc((size_t)(N + 1) * 4);
    int*   cursor = (int*)alloc((size_t)N * 4);
    float* dinv   = (float*)alloc((size_t)N * 4);
    int2*  cw     = (int2*)alloc((size_t)E * 8);
    float* hbuf   = (float*)alloc((size_t)N * 32 * 4);
    float* atime  = (float*)alloc((size_t)N * 12 * 4);
    float* ahh    = (float*)alloc((size_t)N * 32 * 4);
    float* small  = (float*)alloc(4624 * 4);
    int*   bsum   = (int*)alloc((size_t)nb * 4);
    int*   boffs  = (int*)alloc((size_t)nb * 4);

    prep_kernel<<<1, 256, 0, stream>>>(W1, b1, Wl1, bl1, att1, W2, b2, Wl2, bl2, att2, small);
    zero2_ints<<<(N + 255) / 256, 256, 0, stream>>>(cnt, cursor, N);
    count_edges<<<(E + 255) / 256, 256, 0, stream>>>(dstp, cnt, E);
    scan_blocksum<<<nb, 256, 0, stream>>>(cnt, dinv, bsum, N);
    scan_boffs<<<1, 64, 0, stream>>>(bsum, boffs, rowptr, nb, N);
    scan_write<<<nb, 256, 0, stream>>>(cnt, boffs, rowptr, N);
    scatter_edges<<<(E + 255) / 256, 256, 0, stream>>>(srcp, dstp, dinv, rowptr, cursor, cw, E);
    agg1_layer1<<<(N * 32 + 255) / 256, 256, 0, stream>>>(x1, rowptr, cw, dinv, small, hbuf, atime, N);
    agg2<<<(N * 32 + 255) / 256, 256, 0, stream>>>(hbuf, rowptr, cw, dinv, ahh, N);
    layer2_final<<<2048, 256, 0, stream>>>(ahh, atime, small, lw1, lb1, lw2, lb2, (float*)d_out, N);
}

// Round 7
// 202.105 us; speedup vs baseline: 2.2245x; 1.0871x over previous
//
#include <hip/hip_runtime.h>
#include <hip/hip_bf16.h>
#include <math.h>

// ---------------------------------------------------------------------------
// A3T-GCN two-layer, restructured (see round-1 notes):
//   - H == 0 => R gate dead, cell = (1-Z)*tanh(...)
//   - A_hat commutes with W => one propagation per layer, folded gate matrices
//   - layer2 time channel reuses layer-1 propagation (rank-1 per period)
// Round 7: fuse agg2 into layer2 (edge gather split across wave halves, av
// bounced through per-wave LDS). Hoist s_q/s_lb1/s_lb2/s_lw2 to registers:
// kills the 800K 4-way bank conflict (s_lw2) and cuts LDS 29.2->25.7KB
// (6 blocks/CU). One-rcp gate math. Grid 1536 = 6 blocks/CU exactly.
// ---------------------------------------------------------------------------

__global__ void zero2_ints(int* __restrict__ a, int* __restrict__ b, int n) {
    int i = blockIdx.x * blockDim.x + threadIdx.x;
    if (i < n) { a[i] = 0; b[i] = 0; }
}

__global__ void count_edges(const int* __restrict__ dst, int* __restrict__ cnt, int E) {
    int e = blockIdx.x * blockDim.x + threadIdx.x;
    if (e < E) atomicAdd(&cnt[dst[e]], 1);
}

// --- parallel exclusive scan of cnt -> rowptr, plus dinv ------------------
__global__ __launch_bounds__(256) void scan_blocksum(
    const int* __restrict__ cnt, float* __restrict__ dinv,
    int* __restrict__ bsum, int n) {
    int base = blockIdx.x * 1024 + threadIdx.x * 4;
    int s = 0;
    if (base + 3 < n) {
        int4 v = *(const int4*)(cnt + base);
        dinv[base + 0] = rsqrtf((float)v.x + 1.f);
        dinv[base + 1] = rsqrtf((float)v.y + 1.f);
        dinv[base + 2] = rsqrtf((float)v.z + 1.f);
        dinv[base + 3] = rsqrtf((float)v.w + 1.f);
        s = v.x + v.y + v.z + v.w;
    } else {
        for (int k = 0; k < 4; ++k)
            if (base + k < n) {
                int v = cnt[base + k];
                dinv[base + k] = rsqrtf((float)v + 1.f);
                s += v;
            }
    }
    #pragma unroll
    for (int off = 32; off > 0; off >>= 1) s += __shfl_down(s, off, 64);
    __shared__ int ws[4];
    int lane = threadIdx.x & 63, wid = threadIdx.x >> 6;
    if (lane == 0) ws[wid] = s;
    __syncthreads();
    if (threadIdx.x == 0) bsum[blockIdx.x] = ws[0] + ws[1] + ws[2] + ws[3];
}

__global__ void scan_boffs(const int* __restrict__ bsum, int* __restrict__ boffs,
                           int* __restrict__ rowptr, int nb, int n) {
    int lane = threadIdx.x;
    int carry = 0;
    for (int base = 0; base < nb; base += 64) {
        int i = base + lane;
        int v = (i < nb) ? bsum[i] : 0;
        int orig = v;
        #pragma unroll
        for (int off = 1; off < 64; off <<= 1) {
            int t = __shfl_up(v, off, 64);
            if (lane >= off) v += t;
        }
        if (i < nb) boffs[i] = carry + v - orig;  // exclusive
        carry += __shfl(v, 63, 64);
    }
    if (lane == 0) rowptr[n] = carry;
}

__global__ __launch_bounds__(256) void scan_write(
    const int* __restrict__ cnt, const int* __restrict__ boffs,
    int* __restrict__ rowptr, int n) {
    int base = blockIdx.x * 1024 + threadIdx.x * 4;
    int4 v = make_int4(0, 0, 0, 0);
    if (base + 3 < n) {
        v = *(const int4*)(cnt + base);
    } else {
        if (base + 0 < n) v.x = cnt[base + 0];
        if (base + 1 < n) v.y = cnt[base + 1];
        if (base + 2 < n) v.z = cnt[base + 2];
        if (base + 3 < n) v.w = cnt[base + 3];
    }
    int t0 = v.x, t1 = t0 + v.y, t2 = t1 + v.z, t3 = t2 + v.w;  // inclusive
    int lane = threadIdx.x & 63, wid = threadIdx.x >> 6;
    int sc = t3;
    #pragma unroll
    for (int off = 1; off < 64; off <<= 1) {
        int t = __shfl_up(sc, off, 64);
        if (lane >= off) sc += t;
    }
    __shared__ int ws[4];
    if (lane == 63) ws[wid] = sc;
    __syncthreads();
    int woff = 0;
    for (int w = 0; w < wid; ++w) woff += ws[w];
    int off0 = boffs[blockIdx.x] + woff + sc - t3;  // exclusive at base
    if (base + 3 < n) {
        *(int4*)(rowptr + base) = make_int4(off0, off0 + t0, off0 + t1, off0 + t2);
    } else {
        if (base + 0 < n) rowptr[base + 0] = off0;
        if (base + 1 < n) rowptr[base + 1] = off0 + t0;
        if (base + 2 < n) rowptr[base + 2] = off0 + t1;
        if (base + 3 < n) rowptr[base + 3] = off0 + t2;
    }
}

__global__ void scatter_edges(const int* __restrict__ src, const int* __restrict__ dst,
                              const float* __restrict__ dinv, const int* __restrict__ rowptr,
                              int* __restrict__ cursor, int2* __restrict__ cw, int E) {
    int e = blockIdx.x * blockDim.x + threadIdx.x;
    if (e >= E) return;
    int s = src[e], d = dst[e];
    int pos = atomicAdd(&cursor[d], 1);
    int idx = rowptr[d] + pos;
    cw[idx] = make_int2(s, __float_as_int(dinv[s] * dinv[d]));
}

// small[] layout (floats):
//   [0:32)a0z [32:64)a1z [64:96)c1z [96:128)a0h [128:160)a1h [160:192)c1h [192:204)probs1
//   [256:2304) M2z   [2304:4352) M2h
//   [4352:4416) q2z [4416:4480) q2h [4480:4544) c2z [4544:4608) c2h [4608:4620) probs2
__global__ __launch_bounds__(256) void prep_kernel(
    const float* __restrict__ W1, const float* __restrict__ b1,
    const float* __restrict__ Wl1, const float* __restrict__ bl1,
    const float* __restrict__ att1,
    const float* __restrict__ W2, const float* __restrict__ b2,
    const float* __restrict__ Wl2, const float* __restrict__ bl2,
    const float* __restrict__ att2, float* __restrict__ small) {
    int tid = threadIdx.x;
    for (int t = tid; t < 192; t += blockDim.x) {
        int which = t >> 5, hh = t & 31;
        int g = (which < 3) ? 0 : 2;
        int kind = which % 3;  // 0:a0 1:a1 2:c
        const float* Wl = Wl1 + g * 64 * 32;
        float s = 0.f;
        if (kind < 2) {
            const float* Wr = W1 + g * 2 * 32 + kind * 32;
            for (int k = 0; k < 32; ++k) s += Wr[k] * Wl[k * 32 + hh];
        } else {
            const float* br = b1 + g * 32;
            for (int k = 0; k < 32; ++k) s += br[k] * Wl[k * 32 + hh];
            s += bl1[g * 32 + hh];
        }
        small[t] = s;
    }
    for (int t = tid; t < 4096; t += blockDim.x) {
        int gg = t >> 11;
        int rem = t & 2047;
        int i = rem >> 6, j = rem & 63;
        int g = gg ? 2 : 0;
        const float* Wl = Wl2 + g * 128 * 64;
        const float* Wr = W2 + g * 33 * 64 + i * 64;
        float s = 0.f;
        for (int k = 0; k < 64; ++k) s += Wr[k] * Wl[k * 64 + j];
        small[256 + gg * 2048 + i * 64 + j] = s;
    }
    for (int t = tid; t < 256; t += blockDim.x) {
        int which = t >> 6, j = t & 63;
        int g = (which == 0 || which == 2) ? 0 : 2;
        const float* Wl = Wl2 + g * 128 * 64;
        float s = 0.f;
        if (which < 2) {
            const float* Wr = W2 + g * 33 * 64 + 32 * 64;
            for (int k = 0; k < 64; ++k) s += Wr[k] * Wl[k * 64 + j];
        } else {
            const float* br = b2 + g * 64;
            for (int k = 0; k < 64; ++k) s += br[k] * Wl[k * 64 + j];
            s += bl2[g * 64 + j];
        }
        small[4352 + which * 64 + j] = s;
    }
    if (tid == 0) {
        float mx = att1[0];
        for (int p = 1; p < 12; ++p) mx = fmaxf(mx, att1[p]);
        float e[12], sm = 0.f;
        for (int p = 0; p < 12; ++p) { e[p] = expf(att1[p] - mx); sm += e[p]; }
        for (int p = 0; p < 12; ++p) small[192 + p] = e[p] / sm;
        mx = att2[0];
        for (int p = 1; p < 12; ++p) mx = fmaxf(mx, att2[p]);
        sm = 0.f;
        for (int p = 0; p < 12; ++p) { e[p] = expf(att2[p] - mx); sm += e[p]; }
        for (int p = 0; p < 12; ++p) small[4608 + p] = e[p] / sm;
    }
}

// One 32-lane group per node. Lanes 0..23 aggregate A_hat x1 (24 ch);
// edge loop unrolled x4 for memory-level parallelism.
__global__ __launch_bounds__(256) void agg1_layer1(
    const float* __restrict__ X, const int* __restrict__ rowptr,
    const int2* __restrict__ cw, const float* __restrict__ dinv,
    const float* __restrict__ small,
    float* __restrict__ hout, float* __restrict__ atime, int n) {
    int lane = threadIdx.x & 31;
    int node = (blockIdx.x * blockDim.x + threadIdx.x) >> 5;
    if (node >= n) return;
    int beg = rowptr[node], end = rowptr[node + 1];
    float acc = 0.f;
    if (lane < 24) {
        float dn = dinv[node];
        acc = dn * dn * X[node * 24 + lane];
        float a0 = 0.f, a1 = 0.f, a2 = 0.f, a3 = 0.f;
        int j = beg;
        for (; j + 4 <= end; j += 4) {
            int2 c0 = cw[j], c1 = cw[j + 1], c2 = cw[j + 2], c3 = cw[j + 3];
            a0 = fmaf(__int_as_float(c0.y), X[c0.x * 24 + lane], a0);
            a1 = fmaf(__int_as_float(c1.y), X[c1.x * 24 + lane], a1);
            a2 = fmaf(__int_as_float(c2.y), X[c2.x * 24 + lane], a2);
            a3 = fmaf(__int_as_float(c3.y), X[c3.x * 24 + lane], a3);
        }
        for (; j < end; ++j) {
            int2 c = cw[j];
            acc = fmaf(__int_as_float(c.y), X[c.x * 24 + lane], acc);
        }
        acc += (a0 + a1) + (a2 + a3);
    }
    if (lane >= 12 && lane < 24) atime[node * 12 + lane - 12] = acc;
    float a0z = small[lane], a1z = small[32 + lane], c1z = small[64 + lane];
    float a0h = small[96 + lane], a1h = small[128 + lane], c1h = small[160 + lane];
    float hs = 0.f;
    #pragma unroll
    for (int p = 0; p < 12; ++p) {
        float x0 = __shfl(acc, p, 32);
        float x1 = __shfl(acc, 12 + p, 32);
        float z = 1.f / (1.f + __expf(-fmaf(x0, a0z, fmaf(x1, a1z, c1z))));
        float ht = tanhf(fmaf(x0, a0h, fmaf(x1, a1h, c1h)));
        hs = fmaf(small[192 + p] * (1.f - z), ht, hs);
    }
    hout[node * 32 + lane] = fmaxf(hs, 0.f);
}

// Fused agg2 + layer2 + final MLP. One 64-lane wave per node.
// Gather: halves split edge list (stride 2), combine via shfl_xor(32);
// av bounced through per-wave LDS scratch, then GEMV from wqs tiles.
// LDS = 16K(wqs) + 8K(lw1) + 64(pr) + 1K(scratch) = 25.7KB -> 6 blocks/CU.
__global__ __launch_bounds__(256, 5) void agg2_layer2(
    const float* __restrict__ hbuf, const float* __restrict__ atime,
    const int* __restrict__ rowptr, const int2* __restrict__ cw,
    const float* __restrict__ dinv, const float* __restrict__ small,
    const float* __restrict__ lw1, const float* __restrict__ lb1,
    const float* __restrict__ lw2, const float* __restrict__ lb2,
    float* __restrict__ out, int n) {
    __shared__ __align__(16) float4 wqs[1024];          // 16 KB M2z/M2h interleaved
    __shared__ __align__(16) float s_lw1[2048];          // 8 KB [j][k] 64x32
    __shared__ float s_pr[16];
    __shared__ __align__(16) float4 scr[4][16];          // per-wave av/h2 scratch

    for (int t = threadIdx.x; t < 4096; t += 256) {
        int s = t & 3, j = (t >> 2) & 63, k2 = t >> 8;
        int k = 2 * k2 + (s >> 1), zh = s & 1;
        ((float*)wqs)[t] = small[256 + zh * 2048 + k * 64 + j];
    }
    for (int t = threadIdx.x; t < 2048; t += 256) s_lw1[t] = lw1[t];
    if (threadIdx.x < 16) s_pr[threadIdx.x] = (threadIdx.x < 12) ? small[4608 + threadIdx.x] : 0.f;
    __syncthreads();

    int lane = threadIdx.x & 63;
    int wid = threadIdx.x >> 6;
    int ch = lane & 31, half = lane >> 5;
    // hoisted per-lane constants (constant across the node loop)
    float qz = small[4352 + lane], qh = small[4416 + lane];
    float czv = small[4480 + lane], chv = small[4544 + lane];
    float lb1v = lb1[ch];
    int p_ = lane & 15, q_ = lane >> 4;
    float lb2v = (q_ == 0 && p_ < 12) ? lb2[p_] : 0.f;
    float wlw2[8];
    #pragma unroll
    for (int i = 0; i < 8; ++i)
        wlw2[i] = (p_ < 12) ? lw2[(q_ * 8 + i) * 12 + p_] : 0.f;

    int totalw = gridDim.x * 4;
    for (int node = blockIdx.x * 4 + wid; node < n; node += totalw) {
        // ---- fused agg2: av[ch] = (A_hat h)[node][ch] ----
        int beg = rowptr[node], end = rowptr[node + 1];
        float dn = dinv[node];
        float acc = (half == 0) ? dn * dn * hbuf[(size_t)node * 32 + ch] : 0.f;
        float acc1 = 0.f;
        int j = beg + half;
        for (; j + 2 < end; j += 4) {
            int2 c0 = cw[j], c1 = cw[j + 2];
            acc  = fmaf(__int_as_float(c0.y), hbuf[(size_t)c0.x * 32 + ch], acc);
            acc1 = fmaf(__int_as_float(c1.y), hbuf[(size_t)c1.x * 32 + ch], acc1);
        }
        if (j < end) {
            int2 c = cw[j];
            acc = fmaf(__int_as_float(c.y), hbuf[(size_t)c.x * 32 + ch], acc);
        }
        acc += acc1;
        acc += __shfl_xor(acc, 32, 64);   // both halves hold av[ch]

        // redistribute av via per-wave LDS (wave-internal, in-order DS pipe)
        if (half == 0) ((float*)&scr[wid][0])[ch] = acc;
        asm volatile("s_waitcnt lgkmcnt(0)" ::: "memory");

        // ---- GEMV: p0z/p0h = av . M2z/M2h (col j=lane) ----
        float p0z = czv, p0h = chv;
        const float4* arow = &scr[wid][0];
        #pragma unroll
        for (int c = 0; c < 8; ++c) {
            float4 av = arow[c];
            float4 w0 = wqs[(2 * c) * 64 + lane];
            float4 w1 = wqs[(2 * c + 1) * 64 + lane];
            p0z = fmaf(av.x, w0.x, p0z); p0h = fmaf(av.x, w0.y, p0h);
            p0z = fmaf(av.y, w0.z, p0z); p0h = fmaf(av.y, w0.w, p0h);
            p0z = fmaf(av.z, w1.x, p0z); p0h = fmaf(av.z, w1.y, p0h);
            p0z = fmaf(av.w, w1.z, p0z); p0h = fmaf(av.w, w1.w, p0h);
        }
        const float4* trow = (const float4*)(atime + (size_t)node * 12);
        float4 tA = trow[0], tB = trow[1], tC = trow[2];
        float tt[12] = {tA.x, tA.y, tA.z, tA.w, tB.x, tB.y, tB.z, tB.w,
                        tC.x, tC.y, tC.z, tC.w};
        float acc2 = 0.f;
        #pragma unroll
        for (int p = 0; p < 12; ++p) {
            float t = tt[p];
            float ez = __expf(-fmaf(t, qz, p0z));
            float eh = __expf(-2.f * fmaf(t, qh, p0h));
            // (1-sig(z))*tanh(h) = ez*(1-eh) / ((1+ez)*(1+eh))  -- one rcp
            float R = __builtin_amdgcn_rcpf((1.f + ez) * (1.f + eh));
            acc2 = fmaf(s_pr[p] * ez * (1.f - eh), R, acc2);
        }
        float h2 = fmaxf(acc2, 0.f);
        ((float*)&scr[wid][0])[lane] = h2;
        asm volatile("s_waitcnt lgkmcnt(0)" ::: "memory");

        // ---- h3 = relu(h2 . lw1 + lb1), split over halves ----
        float h3 = half ? 0.f : lb1v;
        const float4* hrow = &scr[wid][half * 8];
        #pragma unroll
        for (int c = 0; c < 8; ++c) {
            float4 hv = hrow[c];
            int jb = half * 32 + c * 4;
            h3 = fmaf(hv.x, s_lw1[(jb + 0) * 32 + ch], h3);
            h3 = fmaf(hv.y, s_lw1[(jb + 1) * 32 + ch], h3);
            h3 = fmaf(hv.z, s_lw1[(jb + 2) * 32 + ch], h3);
            h3 = fmaf(hv.w, s_lw1[(jb + 3) * 32 + ch], h3);
        }
        h3 += __shfl_xor(h3, 32, 64);
        h3 = fmaxf(h3, 0.f);

        // ---- out = h3 . lw2 + lb2 (lw2 in registers: no LDS conflicts) ----
        float o = lb2v;
        #pragma unroll
        for (int i = 0; i < 8; ++i) {
            float h3k = __shfl(h3, q_ * 8 + i, 64);
            o = fmaf(h3k, wlw2[i], o);
        }
        o += __shfl_xor(o, 16, 64);
        o += __shfl_xor(o, 32, 64);
        if (lane < 12) out[(size_t)node * 12 + lane] = o;
    }
}

extern "C" void kernel_launch(void* const* d_in, const int* in_sizes, int n_in,
                              void* d_out, int out_size, void* d_ws, size_t ws_size,
                              hipStream_t stream) {
    const float* x1   = (const float*)d_in[0];
    const int*   eidx = (const int*)d_in[1];
    const float* W1   = (const float*)d_in[4];
    const float* b1   = (const float*)d_in[5];
    const float* Wl1  = (const float*)d_in[6];
    const float* bl1  = (const float*)d_in[7];
    const float* att1 = (const float*)d_in[8];
    const float* W2   = (const float*)d_in[9];
    const float* b2   = (const float*)d_in[10];
    const float* Wl2  = (const float*)d_in[11];
    const float* bl2  = (const float*)d_in[12];
    const float* att2 = (const float*)d_in[13];
    const float* lw1  = (const float*)d_in[14];
    const float* lb1  = (const float*)d_in[15];
    const float* lw2  = (const float*)d_in[16];
    const float* lb2  = (const float*)d_in[17];
    (void)n_in; (void)out_size; (void)ws_size;

    int N = in_sizes[0] / 24;
    int E = in_sizes[1] / 2;
    const int* srcp = eidx;
    const int* dstp = eidx + E;
    int nb = (N + 1023) / 1024;

    char* ws = (char*)d_ws;
    size_t off = 0;
    auto alloc = [&](size_t bytes) -> char* {
        char* p = ws + off;
        off += (bytes + 511) & ~(size_t)511;
        return p;
    };
    int*   cnt    = (int*)alloc((size_t)N * 4);
    int*   rowptr = (int*)alloc((size_t)(N + 1) * 4);
    int*   cursor = (int*)alloc((size_t)N * 4);
    float* dinv   = (float*)alloc((size_t)N * 4);
    int2*  cw     = (int2*)alloc((size_t)E * 8);
    float* hbuf   = (float*)alloc((size_t)N * 32 * 4);
    float* atime  = (float*)alloc((size_t)N * 12 * 4);
    float* small  = (float*)alloc(4624 * 4);
    int*   bsum   = (int*)alloc((size_t)nb * 4);
    int*   boffs  = (int*)alloc((size_t)nb * 4);

    prep_kernel<<<1, 256, 0, stream>>>(W1, b1, Wl1, bl1, att1, W2, b2, Wl2, bl2, att2, small);
    zero2_ints<<<(N + 255) / 256, 256, 0, stream>>>(cnt, cursor, N);
    count_edges<<<(E + 255) / 256, 256, 0, stream>>>(dstp, cnt, E);
    scan_blocksum<<<nb, 256, 0, stream>>>(cnt, dinv, bsum, N);
    scan_boffs<<<1, 64, 0, stream>>>(bsum, boffs, rowptr, nb, N);
    scan_write<<<nb, 256, 0, stream>>>(cnt, boffs, rowptr, N);
    scatter_edges<<<(E + 255) / 256, 256, 0, stream>>>(srcp, dstp, dinv, rowptr, cursor, cw, E);
    agg1_layer1<<<(N * 32 + 255) / 256, 256, 0, stream>>>(x1, rowptr, cw, dinv, small, hbuf, atime, N);
    agg2_layer2<<<1536, 256, 0, stream>>>(hbuf, atime, rowptr, cw, dinv, small,
                                          lw1, lb1, lw2, lb2, (float*)d_out, N);
}

// Round 8
// 197.989 us; speedup vs baseline: 2.2707x; 1.0208x over previous
//
#include <hip/hip_runtime.h>
#include <hip/hip_bf16.h>
#include <math.h>

// ---------------------------------------------------------------------------
// A3T-GCN two-layer, restructured (see round-1 notes):
//   - H == 0 => R gate dead, cell = (1-Z)*tanh(...)
//   - A_hat commutes with W => one propagation per layer, folded gate matrices
//   - layer2 time channel reuses layer-1 propagation (rank-1 per period)
// Round 8: bf16 gather operands. x1->bf16 copy (2.4MB) and hbuf stored bf16
// (3.2MB) both fit a single XCD's 4MB L2 -> random edge gathers become
// L2-resident (round-7 FETCH_SIZE showed 36.7MB HBM/L3 traffic for a 6.4MB
// buffer). agg2 gather unrolled to 4 streams/half. Self-terms stay f32.
// ---------------------------------------------------------------------------

static __device__ __forceinline__ unsigned short f2bf(float f) {
    unsigned u = __float_as_uint(f);
    unsigned r = (u + 0x7FFFu + ((u >> 16) & 1u)) >> 16;  // RNE
    return (unsigned short)r;
}
static __device__ __forceinline__ float bf2f(unsigned short u) {
    return __uint_as_float(((unsigned)u) << 16);
}

__global__ void zero2_ints(int* __restrict__ a, int* __restrict__ b, int n) {
    int i = blockIdx.x * blockDim.x + threadIdx.x;
    if (i < n) { a[i] = 0; b[i] = 0; }
}

__global__ void cvt_bf16(const float* __restrict__ in, unsigned short* __restrict__ out, int n) {
    int i = (blockIdx.x * blockDim.x + threadIdx.x) * 4;
    if (i + 3 < n) {
        float4 v = *(const float4*)(in + i);
        ushort4 u = make_ushort4(f2bf(v.x), f2bf(v.y), f2bf(v.z), f2bf(v.w));
        *(ushort4*)(out + i) = u;
    } else {
        for (int k = 0; k < 4; ++k)
            if (i + k < n) out[i + k] = f2bf(in[i + k]);
    }
}

__global__ void count_edges(const int* __restrict__ dst, int* __restrict__ cnt, int E) {
    int e = blockIdx.x * blockDim.x + threadIdx.x;
    if (e < E) atomicAdd(&cnt[dst[e]], 1);
}

// --- parallel exclusive scan of cnt -> rowptr, plus dinv ------------------
__global__ __launch_bounds__(256) void scan_blocksum(
    const int* __restrict__ cnt, float* __restrict__ dinv,
    int* __restrict__ bsum, int n) {
    int base = blockIdx.x * 1024 + threadIdx.x * 4;
    int s = 0;
    if (base + 3 < n) {
        int4 v = *(const int4*)(cnt + base);
        dinv[base + 0] = rsqrtf((float)v.x + 1.f);
        dinv[base + 1] = rsqrtf((float)v.y + 1.f);
        dinv[base + 2] = rsqrtf((float)v.z + 1.f);
        dinv[base + 3] = rsqrtf((float)v.w + 1.f);
        s = v.x + v.y + v.z + v.w;
    } else {
        for (int k = 0; k < 4; ++k)
            if (base + k < n) {
                int v = cnt[base + k];
                dinv[base + k] = rsqrtf((float)v + 1.f);
                s += v;
            }
    }
    #pragma unroll
    for (int off = 32; off > 0; off >>= 1) s += __shfl_down(s, off, 64);
    __shared__ int ws[4];
    int lane = threadIdx.x & 63, wid = threadIdx.x >> 6;
    if (lane == 0) ws[wid] = s;
    __syncthreads();
    if (threadIdx.x == 0) bsum[blockIdx.x] = ws[0] + ws[1] + ws[2] + ws[3];
}

__global__ void scan_boffs(const int* __restrict__ bsum, int* __restrict__ boffs,
                           int* __restrict__ rowptr, int nb, int n) {
    int lane = threadIdx.x;
    int carry = 0;
    for (int base = 0; base < nb; base += 64) {
        int i = base + lane;
        int v = (i < nb) ? bsum[i] : 0;
        int orig = v;
        #pragma unroll
        for (int off = 1; off < 64; off <<= 1) {
            int t = __shfl_up(v, off, 64);
            if (lane >= off) v += t;
        }
        if (i < nb) boffs[i] = carry + v - orig;  // exclusive
        carry += __shfl(v, 63, 64);
    }
    if (lane == 0) rowptr[n] = carry;
}

__global__ __launch_bounds__(256) void scan_write(
    const int* __restrict__ cnt, const int* __restrict__ boffs,
    int* __restrict__ rowptr, int n) {
    int base = blockIdx.x * 1024 + threadIdx.x * 4;
    int4 v = make_int4(0, 0, 0, 0);
    if (base + 3 < n) {
        v = *(const int4*)(cnt + base);
    } else {
        if (base + 0 < n) v.x = cnt[base + 0];
        if (base + 1 < n) v.y = cnt[base + 1];
        if (base + 2 < n) v.z = cnt[base + 2];
        if (base + 3 < n) v.w = cnt[base + 3];
    }
    int t0 = v.x, t1 = t0 + v.y, t2 = t1 + v.z, t3 = t2 + v.w;  // inclusive
    int lane = threadIdx.x & 63, wid = threadIdx.x >> 6;
    int sc = t3;
    #pragma unroll
    for (int off = 1; off < 64; off <<= 1) {
        int t = __shfl_up(sc, off, 64);
        if (lane >= off) sc += t;
    }
    __shared__ int ws[4];
    if (lane == 63) ws[wid] = sc;
    __syncthreads();
    int woff = 0;
    for (int w = 0; w < wid; ++w) woff += ws[w];
    int off0 = boffs[blockIdx.x] + woff + sc - t3;  // exclusive at base
    if (base + 3 < n) {
        *(int4*)(rowptr + base) = make_int4(off0, off0 + t0, off0 + t1, off0 + t2);
    } else {
        if (base + 0 < n) rowptr[base + 0] = off0;
        if (base + 1 < n) rowptr[base + 1] = off0 + t0;
        if (base + 2 < n) rowptr[base + 2] = off0 + t1;
        if (base + 3 < n) rowptr[base + 3] = off0 + t2;
    }
}

__global__ void scatter_edges(const int* __restrict__ src, const int* __restrict__ dst,
                              const float* __restrict__ dinv, const int* __restrict__ rowptr,
                              int* __restrict__ cursor, int2* __restrict__ cw, int E) {
    int e = blockIdx.x * blockDim.x + threadIdx.x;
    if (e >= E) return;
    int s = src[e], d = dst[e];
    int pos = atomicAdd(&cursor[d], 1);
    int idx = rowptr[d] + pos;
    cw[idx] = make_int2(s, __float_as_int(dinv[s] * dinv[d]));
}

// small[] layout (floats):
//   [0:32)a0z [32:64)a1z [64:96)c1z [96:128)a0h [128:160)a1h [160:192)c1h [192:204)probs1
//   [256:2304) M2z   [2304:4352) M2h
//   [4352:4416) q2z [4416:4480) q2h [4480:4544) c2z [4544:4608) c2h [4608:4620) probs2
__global__ __launch_bounds__(256) void prep_kernel(
    const float* __restrict__ W1, const float* __restrict__ b1,
    const float* __restrict__ Wl1, const float* __restrict__ bl1,
    const float* __restrict__ att1,
    const float* __restrict__ W2, const float* __restrict__ b2,
    const float* __restrict__ Wl2, const float* __restrict__ bl2,
    const float* __restrict__ att2, float* __restrict__ small) {
    int tid = threadIdx.x;
    for (int t = tid; t < 192; t += blockDim.x) {
        int which = t >> 5, hh = t & 31;
        int g = (which < 3) ? 0 : 2;
        int kind = which % 3;  // 0:a0 1:a1 2:c
        const float* Wl = Wl1 + g * 64 * 32;
        float s = 0.f;
        if (kind < 2) {
            const float* Wr = W1 + g * 2 * 32 + kind * 32;
            for (int k = 0; k < 32; ++k) s += Wr[k] * Wl[k * 32 + hh];
        } else {
            const float* br = b1 + g * 32;
            for (int k = 0; k < 32; ++k) s += br[k] * Wl[k * 32 + hh];
            s += bl1[g * 32 + hh];
        }
        small[t] = s;
    }
    for (int t = tid; t < 4096; t += blockDim.x) {
        int gg = t >> 11;
        int rem = t & 2047;
        int i = rem >> 6, j = rem & 63;
        int g = gg ? 2 : 0;
        const float* Wl = Wl2 + g * 128 * 64;
        const float* Wr = W2 + g * 33 * 64 + i * 64;
        float s = 0.f;
        for (int k = 0; k < 64; ++k) s += Wr[k] * Wl[k * 64 + j];
        small[256 + gg * 2048 + i * 64 + j] = s;
    }
    for (int t = tid; t < 256; t += blockDim.x) {
        int which = t >> 6, j = t & 63;
        int g = (which == 0 || which == 2) ? 0 : 2;
        const float* Wl = Wl2 + g * 128 * 64;
        float s = 0.f;
        if (which < 2) {
            const float* Wr = W2 + g * 33 * 64 + 32 * 64;
            for (int k = 0; k < 64; ++k) s += Wr[k] * Wl[k * 64 + j];
        } else {
            const float* br = b2 + g * 64;
            for (int k = 0; k < 64; ++k) s += br[k] * Wl[k * 64 + j];
            s += bl2[g * 64 + j];
        }
        small[4352 + which * 64 + j] = s;
    }
    if (tid == 0) {
        float mx = att1[0];
        for (int p = 1; p < 12; ++p) mx = fmaxf(mx, att1[p]);
        float e[12], sm = 0.f;
        for (int p = 0; p < 12; ++p) { e[p] = expf(att1[p] - mx); sm += e[p]; }
        for (int p = 0; p < 12; ++p) small[192 + p] = e[p] / sm;
        mx = att2[0];
        for (int p = 1; p < 12; ++p) mx = fmaxf(mx, att2[p]);
        sm = 0.f;
        for (int p = 0; p < 12; ++p) { e[p] = expf(att2[p] - mx); sm += e[p]; }
        for (int p = 0; p < 12; ++p) small[4608 + p] = e[p] / sm;
    }
}

// One 32-lane group per node. Lanes 0..23 aggregate A_hat x1 (24 ch);
// neighbor gather from bf16 copy (L2-resident), self-term from f32.
// Writes hbuf as bf16 so layer2's gather is L2-resident too.
__global__ __launch_bounds__(256) void agg1_layer1(
    const float* __restrict__ X, const unsigned short* __restrict__ Xh,
    const int* __restrict__ rowptr, const int2* __restrict__ cw,
    const float* __restrict__ dinv, const float* __restrict__ small,
    unsigned short* __restrict__ hout, float* __restrict__ atime, int n) {
    int lane = threadIdx.x & 31;
    int node = (blockIdx.x * blockDim.x + threadIdx.x) >> 5;
    if (node >= n) return;
    int beg = rowptr[node], end = rowptr[node + 1];
    float acc = 0.f;
    if (lane < 24) {
        float dn = dinv[node];
        acc = dn * dn * X[node * 24 + lane];
        float a0 = 0.f, a1 = 0.f, a2 = 0.f, a3 = 0.f;
        int j = beg;
        for (; j + 4 <= end; j += 4) {
            int2 c0 = cw[j], c1 = cw[j + 1], c2 = cw[j + 2], c3 = cw[j + 3];
            a0 = fmaf(__int_as_float(c0.y), bf2f(Xh[c0.x * 24 + lane]), a0);
            a1 = fmaf(__int_as_float(c1.y), bf2f(Xh[c1.x * 24 + lane]), a1);
            a2 = fmaf(__int_as_float(c2.y), bf2f(Xh[c2.x * 24 + lane]), a2);
            a3 = fmaf(__int_as_float(c3.y), bf2f(Xh[c3.x * 24 + lane]), a3);
        }
        for (; j < end; ++j) {
            int2 c = cw[j];
            acc = fmaf(__int_as_float(c.y), bf2f(Xh[c.x * 24 + lane]), acc);
        }
        acc += (a0 + a1) + (a2 + a3);
    }
    if (lane >= 12 && lane < 24) atime[node * 12 + lane - 12] = acc;
    float a0z = small[lane], a1z = small[32 + lane], c1z = small[64 + lane];
    float a0h = small[96 + lane], a1h = small[128 + lane], c1h = small[160 + lane];
    float hs = 0.f;
    #pragma unroll
    for (int p = 0; p < 12; ++p) {
        float x0 = __shfl(acc, p, 32);
        float x1 = __shfl(acc, 12 + p, 32);
        float z = 1.f / (1.f + __expf(-fmaf(x0, a0z, fmaf(x1, a1z, c1z))));
        float ht = tanhf(fmaf(x0, a0h, fmaf(x1, a1h, c1h)));
        hs = fmaf(small[192 + p] * (1.f - z), ht, hs);
    }
    hout[node * 32 + lane] = f2bf(fmaxf(hs, 0.f));
}

// Fused agg2 + layer2 + final MLP. One 64-lane wave per node.
// Gather from bf16 hbuf (3.2MB, per-XCD-L2-resident), 4 streams per half.
__global__ __launch_bounds__(256, 6) void agg2_layer2(
    const unsigned short* __restrict__ hbuf, const float* __restrict__ atime,
    const int* __restrict__ rowptr, const int2* __restrict__ cw,
    const float* __restrict__ dinv, const float* __restrict__ small,
    const float* __restrict__ lw1, const float* __restrict__ lb1,
    const float* __restrict__ lw2, const float* __restrict__ lb2,
    float* __restrict__ out, int n) {
    __shared__ __align__(16) float4 wqs[1024];          // 16 KB M2z/M2h interleaved
    __shared__ __align__(16) float s_lw1[2048];          // 8 KB [j][k] 64x32
    __shared__ float s_pr[16];
    __shared__ __align__(16) float4 scr[4][16];          // per-wave av/h2 scratch

    for (int t = threadIdx.x; t < 4096; t += 256) {
        int s = t & 3, j = (t >> 2) & 63, k2 = t >> 8;
        int k = 2 * k2 + (s >> 1), zh = s & 1;
        ((float*)wqs)[t] = small[256 + zh * 2048 + k * 64 + j];
    }
    for (int t = threadIdx.x; t < 2048; t += 256) s_lw1[t] = lw1[t];
    if (threadIdx.x < 16) s_pr[threadIdx.x] = (threadIdx.x < 12) ? small[4608 + threadIdx.x] : 0.f;
    __syncthreads();

    int lane = threadIdx.x & 63;
    int wid = threadIdx.x >> 6;
    int ch = lane & 31, half = lane >> 5;
    float qz = small[4352 + lane], qh = small[4416 + lane];
    float czv = small[4480 + lane], chv = small[4544 + lane];
    float lb1v = lb1[ch];
    int p_ = lane & 15, q_ = lane >> 4;
    float lb2v = (q_ == 0 && p_ < 12) ? lb2[p_] : 0.f;
    float wlw2[8];
    #pragma unroll
    for (int i = 0; i < 8; ++i)
        wlw2[i] = (p_ < 12) ? lw2[(q_ * 8 + i) * 12 + p_] : 0.f;

    int totalw = gridDim.x * 4;
    for (int node = blockIdx.x * 4 + wid; node < n; node += totalw) {
        // ---- fused agg2: av[ch] = (A_hat h)[node][ch], bf16 gather ----
        int beg = rowptr[node], end = rowptr[node + 1];
        float dn = dinv[node];
        float acc = (half == 0) ? dn * dn * bf2f(hbuf[(size_t)node * 32 + ch]) : 0.f;
        float a1 = 0.f, a2 = 0.f, a3 = 0.f;
        int j = beg + half;
        for (; j + 6 < end; j += 8) {
            int2 c0 = cw[j], c1 = cw[j + 2], c2 = cw[j + 4], c3 = cw[j + 6];
            acc = fmaf(__int_as_float(c0.y), bf2f(hbuf[(size_t)c0.x * 32 + ch]), acc);
            a1  = fmaf(__int_as_float(c1.y), bf2f(hbuf[(size_t)c1.x * 32 + ch]), a1);
            a2  = fmaf(__int_as_float(c2.y), bf2f(hbuf[(size_t)c2.x * 32 + ch]), a2);
            a3  = fmaf(__int_as_float(c3.y), bf2f(hbuf[(size_t)c3.x * 32 + ch]), a3);
        }
        for (; j < end; j += 2) {
            int2 c = cw[j];
            acc = fmaf(__int_as_float(c.y), bf2f(hbuf[(size_t)c.x * 32 + ch]), acc);
        }
        acc += (a1 + a2) + a3;
        acc += __shfl_xor(acc, 32, 64);   // both halves hold av[ch]

        if (half == 0) ((float*)&scr[wid][0])[ch] = acc;
        asm volatile("s_waitcnt lgkmcnt(0)" ::: "memory");

        // ---- GEMV: p0z/p0h = av . M2z/M2h (col j=lane) ----
        float p0z = czv, p0h = chv;
        const float4* arow = &scr[wid][0];
        #pragma unroll
        for (int c = 0; c < 8; ++c) {
            float4 av = arow[c];
            float4 w0 = wqs[(2 * c) * 64 + lane];
            float4 w1 = wqs[(2 * c + 1) * 64 + lane];
            p0z = fmaf(av.x, w0.x, p0z); p0h = fmaf(av.x, w0.y, p0h);
            p0z = fmaf(av.y, w0.z, p0z); p0h = fmaf(av.y, w0.w, p0h);
            p0z = fmaf(av.z, w1.x, p0z); p0h = fmaf(av.z, w1.y, p0h);
            p0z = fmaf(av.w, w1.z, p0z); p0h = fmaf(av.w, w1.w, p0h);
        }
        const float4* trow = (const float4*)(atime + (size_t)node * 12);
        float4 tA = trow[0], tB = trow[1], tC = trow[2];
        float tt[12] = {tA.x, tA.y, tA.z, tA.w, tB.x, tB.y, tB.z, tB.w,
                        tC.x, tC.y, tC.z, tC.w};
        float acc2 = 0.f;
        #pragma unroll
        for (int p = 0; p < 12; ++p) {
            float t = tt[p];
            float ez = __expf(-fmaf(t, qz, p0z));
            float eh = __expf(-2.f * fmaf(t, qh, p0h));
            float R = __builtin_amdgcn_rcpf((1.f + ez) * (1.f + eh));
            acc2 = fmaf(s_pr[p] * ez * (1.f - eh), R, acc2);
        }
        float h2 = fmaxf(acc2, 0.f);
        ((float*)&scr[wid][0])[lane] = h2;
        asm volatile("s_waitcnt lgkmcnt(0)" ::: "memory");

        // ---- h3 = relu(h2 . lw1 + lb1), split over halves ----
        float h3 = half ? 0.f : lb1v;
        const float4* hrow = &scr[wid][half * 8];
        #pragma unroll
        for (int c = 0; c < 8; ++c) {
            float4 hv = hrow[c];
            int jb = half * 32 + c * 4;
            h3 = fmaf(hv.x, s_lw1[(jb + 0) * 32 + ch], h3);
            h3 = fmaf(hv.y, s_lw1[(jb + 1) * 32 + ch], h3);
            h3 = fmaf(hv.z, s_lw1[(jb + 2) * 32 + ch], h3);
            h3 = fmaf(hv.w, s_lw1[(jb + 3) * 32 + ch], h3);
        }
        h3 += __shfl_xor(h3, 32, 64);
        h3 = fmaxf(h3, 0.f);

        // ---- out = h3 . lw2 + lb2 (lw2 in registers) ----
        float o = lb2v;
        #pragma unroll
        for (int i = 0; i < 8; ++i) {
            float h3k = __shfl(h3, q_ * 8 + i, 64);
            o = fmaf(h3k, wlw2[i], o);
        }
        o += __shfl_xor(o, 16, 64);
        o += __shfl_xor(o, 32, 64);
        if (lane < 12) out[(size_t)node * 12 + lane] = o;
    }
}

extern "C" void kernel_launch(void* const* d_in, const int* in_sizes, int n_in,
                              void* d_out, int out_size, void* d_ws, size_t ws_size,
                              hipStream_t stream) {
    const float* x1   = (const float*)d_in[0];
    const int*   eidx = (const int*)d_in[1];
    const float* W1   = (const float*)d_in[4];
    const float* b1   = (const float*)d_in[5];
    const float* Wl1  = (const float*)d_in[6];
    const float* bl1  = (const float*)d_in[7];
    const float* att1 = (const float*)d_in[8];
    const float* W2   = (const float*)d_in[9];
    const float* b2   = (const float*)d_in[10];
    const float* Wl2  = (const float*)d_in[11];
    const float* bl2  = (const float*)d_in[12];
    const float* att2 = (const float*)d_in[13];
    const float* lw1  = (const float*)d_in[14];
    const float* lb1  = (const float*)d_in[15];
    const float* lw2  = (const float*)d_in[16];
    const float* lb2  = (const float*)d_in[17];
    (void)n_in; (void)out_size; (void)ws_size;

    int N = in_sizes[0] / 24;
    int E = in_sizes[1] / 2;
    const int* srcp = eidx;
    const int* dstp = eidx + E;
    int nb = (N + 1023) / 1024;

    char* ws = (char*)d_ws;
    size_t off = 0;
    auto alloc = [&](size_t bytes) -> char* {
        char* p = ws + off;
        off += (bytes + 511) & ~(size_t)511;
        return p;
    };
    int*            cnt    = (int*)alloc((size_t)N * 4);
    int*            rowptr = (int*)alloc((size_t)(N + 1) * 4);
    int*            cursor = (int*)alloc((size_t)N * 4);
    float*          dinv   = (float*)alloc((size_t)N * 4);
    int2*           cw     = (int2*)alloc((size_t)E * 8);
    unsigned short* x1h    = (unsigned short*)alloc((size_t)N * 24 * 2);
    unsigned short* hbuf   = (unsigned short*)alloc((size_t)N * 32 * 2);
    float*          atime  = (float*)alloc((size_t)N * 12 * 4);
    float*          small  = (float*)alloc(4624 * 4);
    int*            bsum   = (int*)alloc((size_t)nb * 4);
    int*            boffs  = (int*)alloc((size_t)nb * 4);

    prep_kernel<<<1, 256, 0, stream>>>(W1, b1, Wl1, bl1, att1, W2, b2, Wl2, bl2, att2, small);
    zero2_ints<<<(N + 255) / 256, 256, 0, stream>>>(cnt, cursor, N);
    cvt_bf16<<<(N * 24 / 4 + 255) / 256, 256, 0, stream>>>(x1, x1h, N * 24);
    count_edges<<<(E + 255) / 256, 256, 0, stream>>>(dstp, cnt, E);
    scan_blocksum<<<nb, 256, 0, stream>>>(cnt, dinv, bsum, N);
    scan_boffs<<<1, 64, 0, stream>>>(bsum, boffs, rowptr, nb, N);
    scan_write<<<nb, 256, 0, stream>>>(cnt, boffs, rowptr, N);
    scatter_edges<<<(E + 255) / 256, 256, 0, stream>>>(srcp, dstp, dinv, rowptr, cursor, cw, E);
    agg1_layer1<<<(N * 32 + 255) / 256, 256, 0, stream>>>(x1, x1h, rowptr, cw, dinv, small, hbuf, atime, N);
    agg2_layer2<<<1536, 256, 0, stream>>>(hbuf, atime, rowptr, cw, dinv, small,
                                          lw1, lb1, lw2, lb2, (float*)d_out, N);
}